// Round 2
// baseline (695.966 us; speedup 1.0000x reference)
//
#include <hip/hip_runtime.h>

typedef unsigned short u16;
typedef __attribute__((ext_vector_type(4))) unsigned short u16x4;
typedef __attribute__((ext_vector_type(8))) short bf16x8;
typedef __attribute__((ext_vector_type(4))) float f32x4;

__device__ inline float bf2f(u16 u) {
  union { unsigned int i; float f; } v; v.i = ((unsigned int)u) << 16; return v.f;
}
__device__ inline u16 f2bf(float f) {
  union { float f; unsigned int i; } v; v.f = f;
  unsigned int r = v.i + 0x7fffu + ((v.i >> 16) & 1u);
  return (u16)(r >> 16);
}
// single-instruction pack of two f32 -> 2xbf16 (T12 primitive; no builtin on gfx950)
__device__ inline unsigned int cvt_pk_bf16(float lo, float hi) {
  unsigned int r;
  asm("v_cvt_pk_bf16_f32 %0, %1, %2" : "=v"(r) : "v"(lo), "v"(hi));
  return r;
}

// async global->LDS, 16B per lane; LDS dest = wave-uniform base + lane*16 (m97/m104)
typedef const __attribute__((address_space(1))) unsigned int* gas_t;
typedef __attribute__((address_space(3))) unsigned int* las_t;
__device__ inline void gload_lds16(const u16* g, u16* l) {
  __builtin_amdgcn_global_load_lds((gas_t)(unsigned long long)(const void*)g,
                                   (las_t)(unsigned int)(unsigned long long)(void*)l,
                                   16, 0, 0);
}

// ---------------- fp32 -> bf16 convert (x) ----------------
__global__ __launch_bounds__(256) void cvt_bf16(const float* __restrict__ src,
                                                u16* __restrict__ dst, int n) {
  int i = (blockIdx.x * 256 + threadIdx.x) * 4;
  if (i >= n) return;
  float4 v = *(const float4*)(src + i);
  u16x4 o;
  o.x = f2bf(v.x); o.y = f2bf(v.y); o.z = f2bf(v.z); o.w = f2bf(v.w);
  *(u16x4*)(dst + i) = o;
}

// ---------------- bias concat (fp32): [bq|bk|bv] -> o[3n] ----------------
__global__ __launch_bounds__(256) void concat3(const float* __restrict__ a,
                                               const float* __restrict__ b,
                                               const float* __restrict__ c,
                                               float* __restrict__ o, int n) {
  int i = blockIdx.x * 256 + threadIdx.x;
  if (i >= n) return;
  o[i] = a[i]; o[n + i] = b[i]; o[2 * n + i] = c[i];
}

// ------------- transpose+convert: fp32 src [R][C] -> bf16 dst [C][R] -------
__global__ __launch_bounds__(256) void transpose_f32_bf16(const float* __restrict__ src,
                                                          u16* __restrict__ dst,
                                                          int R, int C) {
  __shared__ u16 tile[32][33];
  int tx = threadIdx.x & 31, ty = threadIdx.x >> 5;  // 32 x 8
  int c0 = blockIdx.x * 32, r0 = blockIdx.y * 32;
  #pragma unroll
  for (int i = ty; i < 32; i += 8)
    tile[i][tx] = f2bf(src[(size_t)(r0 + i) * C + c0 + tx]);
  __syncthreads();
  #pragma unroll
  for (int i = ty; i < 32; i += 8)
    dst[(size_t)(c0 + i) * R + r0 + tx] = tile[tx][i];
}

// ---- per-head V transpose from packed QKV: src row-stride RS, col offset CO ----
__global__ __launch_bounds__(256) void transpose_v(const u16* __restrict__ src,
                                                   u16* __restrict__ VT,
                                                   int B, int S, int H, int RS, int CO) {
  __shared__ u16 tile[32][33];
  int tx = threadIdx.x & 31, ty = threadIdx.x >> 5;
  int s0 = blockIdx.x * 32, d0 = blockIdx.y * 32;
  int bh = blockIdx.z;
  int b = bh / H, h = bh % H;
  #pragma unroll
  for (int i = ty; i < 32; i += 8)
    tile[i][tx] = src[(size_t)(b * S + s0 + i) * RS + CO + h * 64 + d0 + tx];
  __syncthreads();
  #pragma unroll
  for (int i = ty; i < 32; i += 8)
    VT[((size_t)bh * 64 + d0 + i) * S + s0 + tx] = tile[tx][i];
}

// ---------------- GEMM: C[M,N] = A[M,K] @ Bt[N,K]^T + bias, opt relu --------
__global__ __launch_bounds__(256) void gemm_bt(const u16* __restrict__ A,
                                               const u16* __restrict__ Bt,
                                               const float* __restrict__ bias,
                                               u16* __restrict__ C,
                                               int M, int N, int K, int relu) {
  __shared__ u16 As[128 * 32];
  __shared__ u16 Bs[128 * 32];
  const int tid = threadIdx.x;
  const int lane = tid & 63, wid = tid >> 6;
  const int lr = lane & 15, quad = lane >> 4;
  const int wm = (wid >> 1) * 64, wn = (wid & 1) * 64;
  const int m0 = blockIdx.y * 128, n0 = blockIdx.x * 128;
  const int lrow = lane >> 2;
  const int lcol = (lane & 3) * 8;

  f32x4 acc[4][4];
  const f32x4 zero = {0.f, 0.f, 0.f, 0.f};
  #pragma unroll
  for (int mt = 0; mt < 4; ++mt)
    #pragma unroll
    for (int nt = 0; nt < 4; ++nt) acc[mt][nt] = zero;

  for (int k0 = 0; k0 < K; k0 += 32) {
    #pragma unroll
    for (int it = 0; it < 2; ++it) {
      int rbase = wid * 32 + it * 16;
      gload_lds16(A + (size_t)(m0 + rbase + lrow) * K + k0 + lcol, &As[rbase * 32]);
      gload_lds16(Bt + (size_t)(n0 + rbase + lrow) * K + k0 + lcol, &Bs[rbase * 32]);
    }
    __syncthreads();
    bf16x8 af[4], bfr[4];
    #pragma unroll
    for (int mt = 0; mt < 4; ++mt)
      af[mt] = *(const bf16x8*)(&As[(wm + mt * 16 + lr) * 32 + quad * 8]);
    #pragma unroll
    for (int nt = 0; nt < 4; ++nt)
      bfr[nt] = *(const bf16x8*)(&Bs[(wn + nt * 16 + lr) * 32 + quad * 8]);
    #pragma unroll
    for (int mt = 0; mt < 4; ++mt)
      #pragma unroll
      for (int nt = 0; nt < 4; ++nt)
        acc[mt][nt] = __builtin_amdgcn_mfma_f32_16x16x32_bf16(af[mt], bfr[nt], acc[mt][nt], 0, 0, 0);
    __syncthreads();
  }

  #pragma unroll
  for (int nt = 0; nt < 4; ++nt) {
    int n = n0 + wn + nt * 16 + lr;
    float bv = bias[n];
    #pragma unroll
    for (int mt = 0; mt < 4; ++mt) {
      #pragma unroll
      for (int i = 0; i < 4; ++i) {
        int m = m0 + wm + mt * 16 + quad * 4 + i;
        float v = acc[mt][nt][i] + bv;
        if (relu) v = fmaxf(v, 0.f);
        C[(size_t)m * N + n] = f2bf(v);
      }
    }
  }
}

// ---------------- flash attention (S^T, 16 q-rows per wave) ----------------
// grid: (S/64, B*H); block 256 (4 waves).
// R7: T3-minimum 2-phase — double-buffered K/V, STAGE(t+1) issued BEFORE
//     compute(t), single __syncthreads per tile (was: stage->barrier->compute
//     ->barrier, which drained vmcnt(0) right after issue = full exposed
//     latency every tile). Mask software-pipelined in registers (int4).
//     p_lds stride 72->64 + XOR swizzle => LDS = 40960B exactly = 4 blocks/CU.
__global__ __launch_bounds__(256) void flash_attn(const u16* __restrict__ Qp,
                                                  const u16* __restrict__ Kp,
                                                  const u16* __restrict__ VT,
                                                  const int* __restrict__ mask,
                                                  u16* __restrict__ ctx,
                                                  int B, int S, int H, int QSTR) {
  __shared__ u16 kt_lds[2][64 * 64];     // K tile [krow][dk], linear; XOR-swizzled data
  __shared__ u16 vt_lds[2][64 * 64];     // V^T tile [dk][krow], linear; XOR-swizzled data
  __shared__ u16 p_lds[4 * 16 * 64];     // per-wave P [q][k], XOR-swizzled
  const int tid = threadIdx.x;
  const int lane = tid & 63, wid = tid >> 6;
  const int lr = lane & 15, quad = lane >> 4;
  const int bh = blockIdx.y;
  const int b = bh / H, h = bh % H;
  const int q0 = blockIdx.x * 64;
  const u16* vt_base = VT + (size_t)bh * 64 * S;
  const int* mbase = mask + b * S;
  const float SC = 0.125f * 1.44269504089f;   // 1/sqrt(dk) * log2(e)

  // staging geometry: each wave stages rows [wid*16, wid*16+16) of K and V^T.
  // LDS dest is linear (base + lane*16B); data swizzle applied on the GLOBAL
  // source column so that LDS[row][c] holds element d = c ^ ((row&7)<<3).
  const int srl = lane >> 3;                         // row-within-8 = row&7
  const int scol = ((lane & 7) ^ srl) * 8;           // pre-swizzled source col (u16)
  const int swz = (lr & 7) << 3;                     // read-side swizzle (u16)

  // Q fragments (MFMA B-operand: B[n=q=lane&15][k=quad*8+j])
  bf16x8 qf[2];
  {
    int qm = q0 + wid * 16 + lr;
    const u16* qptr = Qp + (size_t)(b * S + qm) * QSTR + h * 64;
    qf[0] = *(const bf16x8*)(qptr + quad * 8);
    qf[1] = *(const bf16x8*)(qptr + 32 + quad * 8);
  }

  float m_i = -1e30f, l_i = 0.f;        // l_i: per-lane partial (reduced in epilogue)
  f32x4 O[4];                           // O^T accumulators: d = nt*16+quad*4+i, q = lr
  #pragma unroll
  for (int nt = 0; nt < 4; ++nt) {
    O[nt][0] = 0.f; O[nt][1] = 0.f; O[nt][2] = 0.f; O[nt][3] = 0.f;
  }

  u16* pw = &p_lds[wid * 16 * 64 + lr * 64];
  const u16* kgp = Kp + ((size_t)b * S + wid * 16 + srl) * QSTR + h * 64 + scol;
  const u16* vgp = vt_base + (size_t)(wid * 16 + srl) * S + scol;
  u16* klb0 = &kt_lds[0][(wid * 16) * 64];
  u16* vlb0 = &vt_lds[0][(wid * 16) * 64];
  u16* klb1 = &kt_lds[1][(wid * 16) * 64];
  u16* vlb1 = &vt_lds[1][(wid * 16) * 64];

  // prologue: stage tile 0 into buf 0, prefetch mask tile 0 into regs
  gload_lds16(kgp, klb0);
  gload_lds16(kgp + 8 * (size_t)QSTR, klb0 + 8 * 64);
  gload_lds16(vgp, vlb0);
  gload_lds16(vgp + 8 * (size_t)S, vlb0 + 8 * 64);
  int4 mk_nxt[4];
  #pragma unroll
  for (int st = 0; st < 4; ++st)
    mk_nxt[st] = *(const int4*)(mbase + st * 16 + quad * 4);
  __syncthreads();

  int cur = 0;
  for (int kt = 0; kt < S; kt += 64) {
    // rotate mask pipeline, then issue next-tile staging (hides under compute)
    int4 mk[4];
    #pragma unroll
    for (int st = 0; st < 4; ++st) mk[st] = mk_nxt[st];
    if (kt + 64 < S) {
      u16* klb = cur ? klb0 : klb1;
      u16* vlb = cur ? vlb0 : vlb1;
      gload_lds16(kgp + (size_t)(kt + 64) * QSTR, klb);
      gload_lds16(kgp + (size_t)(kt + 72) * QSTR, klb + 8 * 64);
      gload_lds16(vgp + kt + 64, vlb);
      gload_lds16(vgp + 8 * (size_t)S + kt + 64, vlb + 8 * 64);
      #pragma unroll
      for (int st = 0; st < 4; ++st)
        mk_nxt[st] = *(const int4*)(mbase + kt + 64 + st * 16 + quad * 4);
    }
    const u16* kl = kt_lds[cur];
    const u16* vl = vt_lds[cur];

    // S^T (log2 domain): col(lane&15)=q, row(quad*4+i)=k-pos
    float s[4][4];
    __builtin_amdgcn_s_setprio(1);
    #pragma unroll
    for (int st = 0; st < 4; ++st) {
      f32x4 c = {0.f, 0.f, 0.f, 0.f};
      const u16* kr = &kl[(st * 16 + lr) * 64];
      bf16x8 kf0 = *(const bf16x8*)(kr + ((quad * 8) ^ swz));
      bf16x8 kf1 = *(const bf16x8*)(kr + ((32 + quad * 8) ^ swz));
      c = __builtin_amdgcn_mfma_f32_16x16x32_bf16(kf0, qf[0], c, 0, 0, 0);
      c = __builtin_amdgcn_mfma_f32_16x16x32_bf16(kf1, qf[1], c, 0, 0, 0);
      s[st][0] = c[0] * SC + (mk[st].x ? 0.f : -1e30f);
      s[st][1] = c[1] * SC + (mk[st].y ? 0.f : -1e30f);
      s[st][2] = c[2] * SC + (mk[st].z ? 0.f : -1e30f);
      s[st][3] = c[3] * SC + (mk[st].w ? 0.f : -1e30f);
    }
    __builtin_amdgcn_s_setprio(0);

    // online softmax with defer-max (T13): skip rescale while max growth <= 8
    float tmax = s[0][0];
    #pragma unroll
    for (int st = 0; st < 4; ++st)
      #pragma unroll
      for (int i = 0; i < 4; ++i) tmax = fmaxf(tmax, s[st][i]);
    tmax = fmaxf(tmax, __shfl_xor(tmax, 16, 64));
    tmax = fmaxf(tmax, __shfl_xor(tmax, 32, 64));
    if (__any(tmax > m_i + 8.0f)) {
      float mn = fmaxf(m_i, tmax);
      float al = exp2f(m_i - mn);
      m_i = mn;
      l_i *= al;
      #pragma unroll
      for (int nt = 0; nt < 4; ++nt) {
        O[nt][0] *= al; O[nt][1] *= al; O[nt][2] *= al; O[nt][3] *= al;
      }
    }
    float rs = 0.f;
    #pragma unroll
    for (int st = 0; st < 4; ++st)
      #pragma unroll
      for (int i = 0; i < 4; ++i) {
        float p = exp2f(s[st][i] - m_i);
        s[st][i] = p; rs += p;
      }
    l_i += rs;

    // P[q][k] to per-wave LDS (XOR-swizzled): one ds_write_b64 per st
    #pragma unroll
    for (int st = 0; st < 4; ++st) {
      uint2 pk;
      pk.x = cvt_pk_bf16(s[st][0], s[st][1]);
      pk.y = cvt_pk_bf16(s[st][2], s[st][3]);
      *(uint2*)(&pw[(st * 16 + quad * 4) ^ swz]) = pk;
    }

    // O^T += (P@V)^T, accumulated in place
    bf16x8 pf0 = *(const bf16x8*)(&pw[(quad * 8) ^ swz]);
    bf16x8 pf1 = *(const bf16x8*)(&pw[(32 + quad * 8) ^ swz]);
    __builtin_amdgcn_s_setprio(1);
    #pragma unroll
    for (int nt = 0; nt < 4; ++nt) {
      const u16* vr = &vl[(nt * 16 + lr) * 64];
      bf16x8 vf0 = *(const bf16x8*)(vr + ((quad * 8) ^ swz));
      bf16x8 vf1 = *(const bf16x8*)(vr + ((32 + quad * 8) ^ swz));
      O[nt] = __builtin_amdgcn_mfma_f32_16x16x32_bf16(vf0, pf0, O[nt], 0, 0, 0);
      O[nt] = __builtin_amdgcn_mfma_f32_16x16x32_bf16(vf1, pf1, O[nt], 0, 0, 0);
    }
    __builtin_amdgcn_s_setprio(0);

    // single barrier per tile: drains next-tile staging (issued ~500 cycles
    // ago, latency hidden under compute) + guards buffer flip
    __syncthreads();
    cur ^= 1;
  }

  // epilogue: finish l reduction across quads, then vectorized 8B stores
  l_i += __shfl_xor(l_i, 16, 64);
  l_i += __shfl_xor(l_i, 32, 64);
  float linv = 1.f / fmaxf(l_i, 1e-30f);
  int q = q0 + wid * 16 + lr;
  u16* op = ctx + (size_t)(b * S + q) * (H * 64) + h * 64;
  #pragma unroll
  for (int nt = 0; nt < 4; ++nt) {
    u16x4 o;
    o.x = f2bf(O[nt][0] * linv); o.y = f2bf(O[nt][1] * linv);
    o.z = f2bf(O[nt][2] * linv); o.w = f2bf(O[nt][3] * linv);
    *(u16x4*)(op + nt * 16 + quad * 4) = o;
  }
}

// ---------------- fused residual add + LayerNorm (vectorized) ----------------
__device__ inline float block_reduce_sum(float v, float* sbuf) {
  #pragma unroll
  for (int m = 1; m < 64; m <<= 1) v += __shfl_xor(v, m, 64);
  int w = threadIdx.x >> 6;
  if ((threadIdx.x & 63) == 0) sbuf[w] = v;
  __syncthreads();
  v = sbuf[0] + sbuf[1] + sbuf[2] + sbuf[3];
  __syncthreads();
  return v;
}

__global__ __launch_bounds__(256) void add_ln(const float* __restrict__ a32,
                                              const u16* __restrict__ a16,
                                              const u16* __restrict__ b,
                                              const float* __restrict__ g,
                                              const float* __restrict__ be,
                                              u16* __restrict__ out16,
                                              float* __restrict__ out32, int D) {
  __shared__ float sbuf[4];
  int row = blockIdx.x;
  size_t base = (size_t)row * D;
  int i = threadIdx.x * 4;
  float v[4];
  {
    u16x4 bv = *(const u16x4*)(b + base + i);
    if (a32) {
      float4 av = *(const float4*)(a32 + base + i);
      v[0] = av.x + bf2f(bv.x); v[1] = av.y + bf2f(bv.y);
      v[2] = av.z + bf2f(bv.z); v[3] = av.w + bf2f(bv.w);
    } else {
      u16x4 av = *(const u16x4*)(a16 + base + i);
      v[0] = bf2f(av.x) + bf2f(bv.x); v[1] = bf2f(av.y) + bf2f(bv.y);
      v[2] = bf2f(av.z) + bf2f(bv.z); v[3] = bf2f(av.w) + bf2f(bv.w);
    }
  }
  float sum = v[0] + v[1] + v[2] + v[3];
  sum = block_reduce_sum(sum, sbuf);
  float mean = sum / (float)D;
  float var = 0.f;
  #pragma unroll
  for (int j = 0; j < 4; ++j) { float d = v[j] - mean; var += d * d; }
  var = block_reduce_sum(var, sbuf);
  float rstd = rsqrtf(var / (float)D + 1e-5f);
  float4 gv = *(const float4*)(g + i);
  float4 bev = *(const float4*)(be + i);
  float o0 = (v[0] - mean) * rstd * gv.x + bev.x;
  float o1 = (v[1] - mean) * rstd * gv.y + bev.y;
  float o2 = (v[2] - mean) * rstd * gv.z + bev.z;
  float o3 = (v[3] - mean) * rstd * gv.w + bev.w;
  if (out32) {
    float4 o = {o0, o1, o2, o3};
    *(float4*)(out32 + base + i) = o;
  } else {
    u16x4 o;
    o.x = f2bf(o0); o.y = f2bf(o1); o.z = f2bf(o2); o.w = f2bf(o3);
    *(u16x4*)(out16 + base + i) = o;
  }
}

// ---------------- launch ----------------
extern "C" void kernel_launch(void* const* d_in, const int* in_sizes, int n_in,
                              void* d_out, int out_size, void* d_ws, size_t ws_size,
                              hipStream_t stream) {
  (void)in_sizes; (void)n_in; (void)out_size; (void)ws_size;
  const float* x   = (const float*)d_in[0];
  const int* mask  = (const int*)d_in[1];
  const float* wq  = (const float*)d_in[2];
  const float* bq  = (const float*)d_in[3];
  const float* wk  = (const float*)d_in[4];
  const float* bk  = (const float*)d_in[5];
  const float* wv  = (const float*)d_in[6];
  const float* bv  = (const float*)d_in[7];
  const float* wo  = (const float*)d_in[8];
  const float* bo  = (const float*)d_in[9];
  const float* w1  = (const float*)d_in[10];
  const float* b1  = (const float*)d_in[11];
  const float* w2  = (const float*)d_in[12];
  const float* b2  = (const float*)d_in[13];
  const float* g1  = (const float*)d_in[14];
  const float* be1 = (const float*)d_in[15];
  const float* g2  = (const float*)d_in[16];
  const float* be2 = (const float*)d_in[17];

  const int B = 4, S = 2048, D = 1024, H = 16, DFF = 4096;
  const int D3 = 3 * D;
  const size_t TOK = (size_t)B * S;
  const size_t TD = TOK * D;

  u16* ws   = (u16*)d_ws;
  u16* QKVp = ws;                          // [0, 3*TD)
  u16* xb   = ws + 3 * TD;                 // dead after QKV gemm
  u16* VT   = xb;
  u16* CTX  = ws + 4 * TD;
  u16* ATT  = ws + 5 * TD;
  u16* Hb   = ws + 6 * TD;
  u16* QKVT = ws + 7 * TD;                 // 3*D*D
  u16* WOT  = QKVT + 3 * (size_t)D * D;    // D*D
  u16* W1T  = WOT + (size_t)D * D;         // D*DFF
  u16* FF1  = ws;                          // overlays QKVp+VT
  u16* FF2  = ATT;
  u16* W2T  = QKVT;                        // into dead QKVT+WOT
  float* biasc = (float*)CTX;              // dead before flash writes CTX

  dim3 blk(256);

  cvt_bf16<<<dim3((unsigned)(TD / (256 * 4))), blk, 0, stream>>>(x, xb, (int)TD);
  concat3<<<dim3(4), blk, 0, stream>>>(bq, bk, bv, biasc, D);

  transpose_f32_bf16<<<dim3(D / 32, D / 32), blk, 0, stream>>>(wq, QKVT, D, D);
  transpose_f32_bf16<<<dim3(D / 32, D / 32), blk, 0, stream>>>(wk, QKVT + (size_t)D * D, D, D);
  transpose_f32_bf16<<<dim3(D / 32, D / 32), blk, 0, stream>>>(wv, QKVT + 2 * (size_t)D * D, D, D);
  transpose_f32_bf16<<<dim3(D / 32, D / 32), blk, 0, stream>>>(wo, WOT, D, D);
  transpose_f32_bf16<<<dim3(DFF / 32, D / 32), blk, 0, stream>>>(w1, W1T, D, DFF);

  gemm_bt<<<dim3(D3 / 128, TOK / 128), blk, 0, stream>>>(xb, QKVT, biasc, QKVp, (int)TOK, D3, D, 0);

  transpose_v<<<dim3(S / 32, 2, B * H), blk, 0, stream>>>(QKVp, VT, B, S, H, D3, 2 * D);

  flash_attn<<<dim3(S / 64, B * H), blk, 0, stream>>>(QKVp, QKVp + D, VT, mask, CTX, B, S, H, D3);

  gemm_bt<<<dim3(D / 128, TOK / 128), blk, 0, stream>>>(CTX, WOT, bo, ATT, (int)TOK, D, D, 0);

  transpose_f32_bf16<<<dim3(D / 32, DFF / 32), blk, 0, stream>>>(w2, W2T, DFF, D);

  add_ln<<<dim3((unsigned)TOK), blk, 0, stream>>>(x, (const u16*)nullptr, ATT, g1, be1,
                                                  Hb, (float*)nullptr, D);

  gemm_bt<<<dim3(DFF / 128, TOK / 128), blk, 0, stream>>>(Hb, W1T, b1, FF1, (int)TOK, DFF, D, 1);
  gemm_bt<<<dim3(D / 128, TOK / 128), blk, 0, stream>>>(FF1, W2T, b2, FF2, (int)TOK, D, DFF, 0);

  add_ln<<<dim3((unsigned)TOK), blk, 0, stream>>>((const float*)nullptr, Hb, FF2, g2, be2,
                                                  (u16*)nullptr, (float*)d_out, D);
}

// Round 3
// 657.789 us; speedup vs baseline: 1.0580x; 1.0580x over previous
//
#include <hip/hip_runtime.h>

typedef unsigned short u16;
typedef __attribute__((ext_vector_type(4))) unsigned short u16x4;
typedef __attribute__((ext_vector_type(8))) short bf16x8;
typedef __attribute__((ext_vector_type(4))) float f32x4;
typedef __attribute__((ext_vector_type(16))) float f32x16;

__device__ inline float bf2f(u16 u) {
  union { unsigned int i; float f; } v; v.i = ((unsigned int)u) << 16; return v.f;
}
__device__ inline u16 f2bf(float f) {
  union { float f; unsigned int i; } v; v.f = f;
  unsigned int r = v.i + 0x7fffu + ((v.i >> 16) & 1u);
  return (u16)(r >> 16);
}
// single-instruction pack of two f32 -> 2xbf16 (T12 primitive; no builtin on gfx950)
__device__ inline unsigned int cvt_pk_bf16(float lo, float hi) {
  unsigned int r;
  asm("v_cvt_pk_bf16_f32 %0, %1, %2" : "=v"(r) : "v"(lo), "v"(hi));
  return r;
}
__device__ inline f32x16 zero16() {
  f32x16 z;
  #pragma unroll
  for (int i = 0; i < 16; ++i) z[i] = 0.f;
  return z;
}

// async global->LDS, 16B per lane; LDS dest = wave-uniform base + lane*16 (m97/m104)
typedef const __attribute__((address_space(1))) unsigned int* gas_t;
typedef __attribute__((address_space(3))) unsigned int* las_t;
__device__ inline void gload_lds16(const u16* g, u16* l) {
  __builtin_amdgcn_global_load_lds((gas_t)(unsigned long long)(const void*)g,
                                   (las_t)(unsigned int)(unsigned long long)(void*)l,
                                   16, 0, 0);
}

// ---------------- fp32 -> bf16 convert (x) ----------------
__global__ __launch_bounds__(256) void cvt_bf16(const float* __restrict__ src,
                                                u16* __restrict__ dst, int n) {
  int i = (blockIdx.x * 256 + threadIdx.x) * 4;
  if (i >= n) return;
  float4 v = *(const float4*)(src + i);
  u16x4 o;
  o.x = f2bf(v.x); o.y = f2bf(v.y); o.z = f2bf(v.z); o.w = f2bf(v.w);
  *(u16x4*)(dst + i) = o;
}

// ---------------- bias concat (fp32): [bq|bk|bv] -> o[3n] ----------------
__global__ __launch_bounds__(256) void concat3(const float* __restrict__ a,
                                               const float* __restrict__ b,
                                               const float* __restrict__ c,
                                               float* __restrict__ o, int n) {
  int i = blockIdx.x * 256 + threadIdx.x;
  if (i >= n) return;
  o[i] = a[i]; o[n + i] = b[i]; o[2 * n + i] = c[i];
}

// ------------- transpose+convert: fp32 src [R][C] -> bf16 dst [C][R] -------
__global__ __launch_bounds__(256) void transpose_f32_bf16(const float* __restrict__ src,
                                                          u16* __restrict__ dst,
                                                          int R, int C) {
  __shared__ u16 tile[32][33];
  int tx = threadIdx.x & 31, ty = threadIdx.x >> 5;  // 32 x 8
  int c0 = blockIdx.x * 32, r0 = blockIdx.y * 32;
  #pragma unroll
  for (int i = ty; i < 32; i += 8)
    tile[i][tx] = f2bf(src[(size_t)(r0 + i) * C + c0 + tx]);
  __syncthreads();
  #pragma unroll
  for (int i = ty; i < 32; i += 8)
    dst[(size_t)(c0 + i) * R + r0 + tx] = tile[tx][i];
}

// ---- per-head V transpose from packed QKV: src row-stride RS, col offset CO ----
__global__ __launch_bounds__(256) void transpose_v(const u16* __restrict__ src,
                                                   u16* __restrict__ VT,
                                                   int B, int S, int H, int RS, int CO) {
  __shared__ u16 tile[32][33];
  int tx = threadIdx.x & 31, ty = threadIdx.x >> 5;
  int s0 = blockIdx.x * 32, d0 = blockIdx.y * 32;
  int bh = blockIdx.z;
  int b = bh / H, h = bh % H;
  #pragma unroll
  for (int i = ty; i < 32; i += 8)
    tile[i][tx] = src[(size_t)(b * S + s0 + i) * RS + CO + h * 64 + d0 + tx];
  __syncthreads();
  #pragma unroll
  for (int i = ty; i < 32; i += 8)
    VT[((size_t)bh * 64 + d0 + i) * S + s0 + tx] = tile[tx][i];
}

// ---------------- GEMM: C[M,N] = A[M,K] @ Bt[N,K]^T + bias, opt relu --------
__global__ __launch_bounds__(256) void gemm_bt(const u16* __restrict__ A,
                                               const u16* __restrict__ Bt,
                                               const float* __restrict__ bias,
                                               u16* __restrict__ C,
                                               int M, int N, int K, int relu) {
  __shared__ u16 As[128 * 32];
  __shared__ u16 Bs[128 * 32];
  const int tid = threadIdx.x;
  const int lane = tid & 63, wid = tid >> 6;
  const int lr = lane & 15, quad = lane >> 4;
  const int wm = (wid >> 1) * 64, wn = (wid & 1) * 64;
  const int m0 = blockIdx.y * 128, n0 = blockIdx.x * 128;
  const int lrow = lane >> 2;
  const int lcol = (lane & 3) * 8;

  f32x4 acc[4][4];
  const f32x4 zero = {0.f, 0.f, 0.f, 0.f};
  #pragma unroll
  for (int mt = 0; mt < 4; ++mt)
    #pragma unroll
    for (int nt = 0; nt < 4; ++nt) acc[mt][nt] = zero;

  for (int k0 = 0; k0 < K; k0 += 32) {
    #pragma unroll
    for (int it = 0; it < 2; ++it) {
      int rbase = wid * 32 + it * 16;
      gload_lds16(A + (size_t)(m0 + rbase + lrow) * K + k0 + lcol, &As[rbase * 32]);
      gload_lds16(Bt + (size_t)(n0 + rbase + lrow) * K + k0 + lcol, &Bs[rbase * 32]);
    }
    __syncthreads();
    bf16x8 af[4], bfr[4];
    #pragma unroll
    for (int mt = 0; mt < 4; ++mt)
      af[mt] = *(const bf16x8*)(&As[(wm + mt * 16 + lr) * 32 + quad * 8]);
    #pragma unroll
    for (int nt = 0; nt < 4; ++nt)
      bfr[nt] = *(const bf16x8*)(&Bs[(wn + nt * 16 + lr) * 32 + quad * 8]);
    #pragma unroll
    for (int mt = 0; mt < 4; ++mt)
      #pragma unroll
      for (int nt = 0; nt < 4; ++nt)
        acc[mt][nt] = __builtin_amdgcn_mfma_f32_16x16x32_bf16(af[mt], bfr[nt], acc[mt][nt], 0, 0, 0);
    __syncthreads();
  }

  #pragma unroll
  for (int nt = 0; nt < 4; ++nt) {
    int n = n0 + wn + nt * 16 + lr;
    float bv = bias[n];
    #pragma unroll
    for (int mt = 0; mt < 4; ++mt) {
      #pragma unroll
      for (int i = 0; i < 4; ++i) {
        int m = m0 + wm + mt * 16 + quad * 4 + i;
        float v = acc[mt][nt][i] + bv;
        if (relu) v = fmaxf(v, 0.f);
        C[(size_t)m * N + n] = f2bf(v);
      }
    }
  }
}

// ---------------- flash attention (S^T, 32 q-rows per wave, 32x32 MFMA) -----
// grid: (S/128, B*H); block 256 (4 waves, each owns 32 q-rows).
// R8: 32x32x16 MFMA halves K/V LDS-read traffic per output; P redistributed
//     IN REGISTERS (cvt_pk + shfl_xor(32) pair exchange) => zero P LDS traffic;
//     mask via __ballot fast path; SC folded into exp2 arg (raw-domain max,
//     THR=44 == exp2(8) P-bound). Single-buffer, 2-barrier (R1 structure).
// 32x32x16 layouts: A[m=lane&31][k=(lane>>5)*8+j], B[n=lane&31][k=(lane>>5)*8+j],
// C/D: col=lane&31, row=(reg&3)+8*(reg>>2)+4*(lane>>5)  [m74/m101 verified].
__global__ __launch_bounds__(256) void flash_attn(const u16* __restrict__ Qp,
                                                  const u16* __restrict__ Kp,
                                                  const u16* __restrict__ VT,
                                                  const int* __restrict__ mask,
                                                  u16* __restrict__ ctx,
                                                  int B, int S, int H, int QSTR) {
  __shared__ u16 kt_lds[64 * 64];        // K tile [k][d], linear; XOR-swizzled data
  __shared__ u16 vt_lds[64 * 64];        // V^T tile [d][k], linear; XOR-swizzled data
  const int tid = threadIdx.x;
  const int lane = tid & 63, wid = tid >> 6;
  const int l31 = lane & 31, hi = lane >> 5;
  const int bh = blockIdx.y;
  const int b = bh / H, h = bh % H;
  const u16* vt_base = VT + (size_t)bh * 64 * S;
  const int* mbase = mask + b * S;
  const float SC = 0.125f * 1.44269504089f;   // 1/sqrt(dk) * log2(e)

  // staging: each wave stages rows [wid*16, wid*16+16) of K and V^T.
  // LDS dest linear; global source col pre-swizzled so LDS[r][c] = M[r][c ^ ((r&7)<<3)].
  const int srl = lane >> 3;                         // row-within-8
  const int scol = ((lane & 7) ^ srl) * 8;           // pre-swizzled source col (u16)
  const int rsw = (lane & 7) << 3;                   // read-side swizzle (row&7 == lane&7)

  // Q fragments: B-operand, q = q0 + l31, k-chunk by hi bit
  const int q = blockIdx.x * 128 + wid * 32 + l31;
  bf16x8 qf[4];
  {
    const u16* qptr = Qp + (size_t)(b * S + q) * QSTR + h * 64;
    #pragma unroll
    for (int t = 0; t < 4; ++t)
      qf[t] = *(const bf16x8*)(qptr + t * 16 + hi * 8);
  }

  float m_i = -1e30f, l_i = 0.f;        // per-lane partials (pair-reduced at end)
  f32x16 o0 = zero16(), o1 = zero16();  // O^T: d-half 0 / 1

  const u16* kgp = Kp + ((size_t)b * S + wid * 16 + srl) * QSTR + h * 64 + scol;
  const u16* vgp = vt_base + (size_t)(wid * 16 + srl) * S + scol;
  u16* klb = &kt_lds[(wid * 16) * 64];
  u16* vlb = &vt_lds[(wid * 16) * 64];

  for (int kt = 0; kt < S; kt += 64) {
    gload_lds16(kgp + (size_t)kt * QSTR, klb);
    gload_lds16(kgp + (size_t)(kt + 8) * QSTR, klb + 8 * 64);
    gload_lds16(vgp + kt, vlb);
    gload_lds16(vgp + 8 * (size_t)S + kt, vlb + 8 * 64);
    int mv = mbase[kt + lane];
    unsigned long long bal = __ballot(mv != 0);
    __syncthreads();

    // ---- S^T = K @ Q^T (raw domain): col = q = l31, row = k via reg pattern
    f32x16 sa0 = zero16(), sa1 = zero16();
    const u16* krow0 = &kt_lds[l31 * 64];
    const u16* krow1 = &kt_lds[(32 + l31) * 64];
    __builtin_amdgcn_s_setprio(1);
    #pragma unroll
    for (int dblock = 0; dblock < 4; ++dblock) {
      int c = (dblock * 16 + hi * 8) ^ rsw;
      bf16x8 kf0 = *(const bf16x8*)(krow0 + c);
      bf16x8 kf1 = *(const bf16x8*)(krow1 + c);
      sa0 = __builtin_amdgcn_mfma_f32_32x32x16_bf16(kf0, qf[dblock], sa0, 0, 0, 0);
      sa1 = __builtin_amdgcn_mfma_f32_32x32x16_bf16(kf1, qf[dblock], sa1, 0, 0, 0);
    }
    __builtin_amdgcn_s_setprio(0);

    // ---- mask (rare path; benchmark mask is all-ones -> skipped entirely)
    if (bal != 0xFFFFFFFFFFFFFFFFull) {
      unsigned long long balh = bal >> (hi * 4);
      #pragma unroll
      for (int r = 0; r < 16; ++r) {
        int kloc = (r & 3) + 8 * (r >> 2);
        if (!((balh >> kloc) & 1)) sa0[r] = -2e30f;
        if (!((balh >> (32 + kloc)) & 1)) sa1[r] = -2e30f;
      }
    }

    // ---- online softmax, defer-max (raw-domain THR = 44 ~ exp2(8) P bound)
    float tmax = sa0[0];
    #pragma unroll
    for (int r = 1; r < 16; ++r) tmax = fmaxf(tmax, sa0[r]);
    #pragma unroll
    for (int r = 0; r < 16; ++r) tmax = fmaxf(tmax, sa1[r]);
    tmax = fmaxf(tmax, __shfl_xor(tmax, 32, 64));
    if (__any(tmax > m_i + 44.0f)) {
      float mn = fmaxf(m_i, tmax);
      float al = exp2f((m_i - mn) * SC);
      m_i = mn;
      l_i *= al;
      #pragma unroll
      for (int r = 0; r < 16; ++r) { o0[r] *= al; o1[r] *= al; }
    }
    float msc = m_i * SC;
    float rs = 0.f;
    #pragma unroll
    for (int r = 0; r < 16; ++r) {
      float p0 = exp2f(__builtin_fmaf(sa0[r], SC, -msc));
      float p1 = exp2f(__builtin_fmaf(sa1[r], SC, -msc));
      sa0[r] = p0; sa1[r] = p1; rs += p0 + p1;
    }
    l_i += rs;

    // ---- P -> bf16 + pair redistribution fully in registers.
    // pf[kb] (kb=2*t2+b1) word layout: w[pair] from even-rq, w[pair+2] from odd-rq;
    // lo lane keeps self-even / takes partner-even; hi takes partner-odd / self-odd.
    unsigned pfw[4][4];
    #pragma unroll
    for (int b1 = 0; b1 < 2; ++b1) {
      #pragma unroll
      for (int pair = 0; pair < 2; ++pair) {
        unsigned X0 = cvt_pk_bf16(sa0[(2 * b1) * 4 + pair * 2], sa0[(2 * b1) * 4 + pair * 2 + 1]);
        unsigned Y0 = cvt_pk_bf16(sa0[(2 * b1 + 1) * 4 + pair * 2], sa0[(2 * b1 + 1) * 4 + pair * 2 + 1]);
        unsigned Xp0 = __shfl_xor(X0, 32, 64);
        unsigned Yp0 = __shfl_xor(Y0, 32, 64);
        pfw[b1][pair] = hi ? Yp0 : X0;
        pfw[b1][pair + 2] = hi ? Y0 : Xp0;
        unsigned X1 = cvt_pk_bf16(sa1[(2 * b1) * 4 + pair * 2], sa1[(2 * b1) * 4 + pair * 2 + 1]);
        unsigned Y1 = cvt_pk_bf16(sa1[(2 * b1 + 1) * 4 + pair * 2], sa1[(2 * b1 + 1) * 4 + pair * 2 + 1]);
        unsigned Xp1 = __shfl_xor(X1, 32, 64);
        unsigned Yp1 = __shfl_xor(Y1, 32, 64);
        pfw[2 + b1][pair] = hi ? Yp1 : X1;
        pfw[2 + b1][pair + 2] = hi ? Y1 : Xp1;
      }
    }

    // ---- O^T += V^T @ P^T
    const u16* vrow0 = &vt_lds[l31 * 64];
    const u16* vrow1 = &vt_lds[(32 + l31) * 64];
    __builtin_amdgcn_s_setprio(1);
    #pragma unroll
    for (int kb = 0; kb < 4; ++kb) {
      int c = (kb * 16 + hi * 8) ^ rsw;
      bf16x8 vf0 = *(const bf16x8*)(vrow0 + c);
      bf16x8 vf1 = *(const bf16x8*)(vrow1 + c);
      union { unsigned w[4]; bf16x8 v; } pu;
      pu.w[0] = pfw[kb][0]; pu.w[1] = pfw[kb][1];
      pu.w[2] = pfw[kb][2]; pu.w[3] = pfw[kb][3];
      o0 = __builtin_amdgcn_mfma_f32_32x32x16_bf16(vf0, pu.v, o0, 0, 0, 0);
      o1 = __builtin_amdgcn_mfma_f32_32x32x16_bf16(vf1, pu.v, o1, 0, 0, 0);
    }
    __builtin_amdgcn_s_setprio(0);
    __syncthreads();
  }

  // epilogue: finish l over the lane pair; d = 8*rq + 4*hi + i (+32 for o1)
  l_i += __shfl_xor(l_i, 32, 64);
  float linv = 1.f / fmaxf(l_i, 1e-30f);
  u16* op = ctx + (size_t)(b * S + q) * (H * 64) + h * 64;
  #pragma unroll
  for (int rq = 0; rq < 4; ++rq) {
    uint2 w0, w1;
    w0.x = cvt_pk_bf16(o0[rq * 4 + 0] * linv, o0[rq * 4 + 1] * linv);
    w0.y = cvt_pk_bf16(o0[rq * 4 + 2] * linv, o0[rq * 4 + 3] * linv);
    *(uint2*)(op + rq * 8 + hi * 4) = w0;
    w1.x = cvt_pk_bf16(o1[rq * 4 + 0] * linv, o1[rq * 4 + 1] * linv);
    w1.y = cvt_pk_bf16(o1[rq * 4 + 2] * linv, o1[rq * 4 + 3] * linv);
    *(uint2*)(op + 32 + rq * 8 + hi * 4) = w1;
  }
}

// ---------------- fused residual add + LayerNorm (vectorized) ----------------
__device__ inline float block_reduce_sum(float v, float* sbuf) {
  #pragma unroll
  for (int m = 1; m < 64; m <<= 1) v += __shfl_xor(v, m, 64);
  int w = threadIdx.x >> 6;
  if ((threadIdx.x & 63) == 0) sbuf[w] = v;
  __syncthreads();
  v = sbuf[0] + sbuf[1] + sbuf[2] + sbuf[3];
  __syncthreads();
  return v;
}

__global__ __launch_bounds__(256) void add_ln(const float* __restrict__ a32,
                                              const u16* __restrict__ a16,
                                              const u16* __restrict__ b,
                                              const float* __restrict__ g,
                                              const float* __restrict__ be,
                                              u16* __restrict__ out16,
                                              float* __restrict__ out32, int D) {
  __shared__ float sbuf[4];
  int row = blockIdx.x;
  size_t base = (size_t)row * D;
  int i = threadIdx.x * 4;
  float v[4];
  {
    u16x4 bv = *(const u16x4*)(b + base + i);
    if (a32) {
      float4 av = *(const float4*)(a32 + base + i);
      v[0] = av.x + bf2f(bv.x); v[1] = av.y + bf2f(bv.y);
      v[2] = av.z + bf2f(bv.z); v[3] = av.w + bf2f(bv.w);
    } else {
      u16x4 av = *(const u16x4*)(a16 + base + i);
      v[0] = bf2f(av.x) + bf2f(bv.x); v[1] = bf2f(av.y) + bf2f(bv.y);
      v[2] = bf2f(av.z) + bf2f(bv.z); v[3] = bf2f(av.w) + bf2f(bv.w);
    }
  }
  float sum = v[0] + v[1] + v[2] + v[3];
  sum = block_reduce_sum(sum, sbuf);
  float mean = sum / (float)D;
  float var = 0.f;
  #pragma unroll
  for (int j = 0; j < 4; ++j) { float d = v[j] - mean; var += d * d; }
  var = block_reduce_sum(var, sbuf);
  float rstd = rsqrtf(var / (float)D + 1e-5f);
  float4 gv = *(const float4*)(g + i);
  float4 bev = *(const float4*)(be + i);
  float o0 = (v[0] - mean) * rstd * gv.x + bev.x;
  float o1 = (v[1] - mean) * rstd * gv.y + bev.y;
  float o2 = (v[2] - mean) * rstd * gv.z + bev.z;
  float o3 = (v[3] - mean) * rstd * gv.w + bev.w;
  if (out32) {
    float4 o = {o0, o1, o2, o3};
    *(float4*)(out32 + base + i) = o;
  } else {
    u16x4 o;
    o.x = f2bf(o0); o.y = f2bf(o1); o.z = f2bf(o2); o.w = f2bf(o3);
    *(u16x4*)(out16 + base + i) = o;
  }
}

// ---------------- launch ----------------
extern "C" void kernel_launch(void* const* d_in, const int* in_sizes, int n_in,
                              void* d_out, int out_size, void* d_ws, size_t ws_size,
                              hipStream_t stream) {
  (void)in_sizes; (void)n_in; (void)out_size; (void)ws_size;
  const float* x   = (const float*)d_in[0];
  const int* mask  = (const int*)d_in[1];
  const float* wq  = (const float*)d_in[2];
  const float* bq  = (const float*)d_in[3];
  const float* wk  = (const float*)d_in[4];
  const float* bk  = (const float*)d_in[5];
  const float* wv  = (const float*)d_in[6];
  const float* bv  = (const float*)d_in[7];
  const float* wo  = (const float*)d_in[8];
  const float* bo  = (const float*)d_in[9];
  const float* w1  = (const float*)d_in[10];
  const float* b1  = (const float*)d_in[11];
  const float* w2  = (const float*)d_in[12];
  const float* b2  = (const float*)d_in[13];
  const float* g1  = (const float*)d_in[14];
  const float* be1 = (const float*)d_in[15];
  const float* g2  = (const float*)d_in[16];
  const float* be2 = (const float*)d_in[17];

  const int B = 4, S = 2048, D = 1024, H = 16, DFF = 4096;
  const int D3 = 3 * D;
  const size_t TOK = (size_t)B * S;
  const size_t TD = TOK * D;

  u16* ws   = (u16*)d_ws;
  u16* QKVp = ws;                          // [0, 3*TD)
  u16* xb   = ws + 3 * TD;                 // dead after QKV gemm
  u16* VT   = xb;
  u16* CTX  = ws + 4 * TD;
  u16* ATT  = ws + 5 * TD;
  u16* Hb   = ws + 6 * TD;
  u16* QKVT = ws + 7 * TD;                 // 3*D*D
  u16* WOT  = QKVT + 3 * (size_t)D * D;    // D*D
  u16* W1T  = WOT + (size_t)D * D;         // D*DFF
  u16* FF1  = ws;                          // overlays QKVp+VT
  u16* FF2  = ATT;
  u16* W2T  = QKVT;                        // into dead QKVT+WOT
  float* biasc = (float*)CTX;              // dead before flash writes CTX

  dim3 blk(256);

  cvt_bf16<<<dim3((unsigned)(TD / (256 * 4))), blk, 0, stream>>>(x, xb, (int)TD);
  concat3<<<dim3(4), blk, 0, stream>>>(bq, bk, bv, biasc, D);

  transpose_f32_bf16<<<dim3(D / 32, D / 32), blk, 0, stream>>>(wq, QKVT, D, D);
  transpose_f32_bf16<<<dim3(D / 32, D / 32), blk, 0, stream>>>(wk, QKVT + (size_t)D * D, D, D);
  transpose_f32_bf16<<<dim3(D / 32, D / 32), blk, 0, stream>>>(wv, QKVT + 2 * (size_t)D * D, D, D);
  transpose_f32_bf16<<<dim3(D / 32, D / 32), blk, 0, stream>>>(wo, WOT, D, D);
  transpose_f32_bf16<<<dim3(DFF / 32, D / 32), blk, 0, stream>>>(w1, W1T, D, DFF);

  gemm_bt<<<dim3(D3 / 128, TOK / 128), blk, 0, stream>>>(xb, QKVT, biasc, QKVp, (int)TOK, D3, D, 0);

  transpose_v<<<dim3(S / 32, 2, B * H), blk, 0, stream>>>(QKVp, VT, B, S, H, D3, 2 * D);

  flash_attn<<<dim3(S / 128, B * H), blk, 0, stream>>>(QKVp, QKVp + D, VT, mask, CTX, B, S, H, D3);

  gemm_bt<<<dim3(D / 128, TOK / 128), blk, 0, stream>>>(CTX, WOT, bo, ATT, (int)TOK, D, D, 0);

  transpose_f32_bf16<<<dim3(D / 32, DFF / 32), blk, 0, stream>>>(w2, W2T, DFF, D);

  add_ln<<<dim3((unsigned)TOK), blk, 0, stream>>>(x, (const u16*)nullptr, ATT, g1, be1,
                                                  Hb, (float*)nullptr, D);

  gemm_bt<<<dim3(DFF / 128, TOK / 128), blk, 0, stream>>>(Hb, W1T, b1, FF1, (int)TOK, DFF, D, 1);
  gemm_bt<<<dim3(D / 128, TOK / 128), blk, 0, stream>>>(FF1, W2T, b2, FF2, (int)TOK, D, DFF, 0);

  add_ln<<<dim3((unsigned)TOK), blk, 0, stream>>>((const float*)nullptr, Hb, FF2, g2, be2,
                                                  (u16*)nullptr, (float*)d_out, D);
}

// Round 4
// 649.995 us; speedup vs baseline: 1.0707x; 1.0120x over previous
//
#include <hip/hip_runtime.h>

typedef unsigned short u16;
typedef __attribute__((ext_vector_type(4))) unsigned short u16x4;
typedef __attribute__((ext_vector_type(8))) short bf16x8;
typedef __attribute__((ext_vector_type(4))) float f32x4;
typedef __attribute__((ext_vector_type(16))) float f32x16;

__device__ inline float bf2f(u16 u) {
  union { unsigned int i; float f; } v; v.i = ((unsigned int)u) << 16; return v.f;
}
__device__ inline u16 f2bf(float f) {
  union { float f; unsigned int i; } v; v.f = f;
  unsigned int r = v.i + 0x7fffu + ((v.i >> 16) & 1u);
  return (u16)(r >> 16);
}
// single-instruction pack of two f32 -> 2xbf16 (T12 primitive; no builtin on gfx950)
__device__ inline unsigned int cvt_pk_bf16(float lo, float hi) {
  unsigned int r;
  asm("v_cvt_pk_bf16_f32 %0, %1, %2" : "=v"(r) : "v"(lo), "v"(hi));
  return r;
}
__device__ inline f32x16 zero16() {
  f32x16 z;
  #pragma unroll
  for (int i = 0; i < 16; ++i) z[i] = 0.f;
  return z;
}

// async global->LDS, 16B per lane; LDS dest = wave-uniform base + lane*16 (m97/m104)
typedef const __attribute__((address_space(1))) unsigned int* gas_t;
typedef __attribute__((address_space(3))) unsigned int* las_t;
__device__ inline void gload_lds16(const u16* g, u16* l) {
  __builtin_amdgcn_global_load_lds((gas_t)(unsigned long long)(const void*)g,
                                   (las_t)(unsigned int)(unsigned long long)(void*)l,
                                   16, 0, 0);
}

// ---------------- fp32 -> bf16 convert (x) ----------------
__global__ __launch_bounds__(256) void cvt_bf16(const float* __restrict__ src,
                                                u16* __restrict__ dst, int n) {
  int i = (blockIdx.x * 256 + threadIdx.x) * 4;
  if (i >= n) return;
  float4 v = *(const float4*)(src + i);
  u16x4 o;
  o.x = f2bf(v.x); o.y = f2bf(v.y); o.z = f2bf(v.z); o.w = f2bf(v.w);
  *(u16x4*)(dst + i) = o;
}

// ---------------- bias concat (fp32): [bq|bk|bv] -> o[3n] ----------------
__global__ __launch_bounds__(256) void concat3(const float* __restrict__ a,
                                               const float* __restrict__ b,
                                               const float* __restrict__ c,
                                               float* __restrict__ o, int n) {
  int i = blockIdx.x * 256 + threadIdx.x;
  if (i >= n) return;
  o[i] = a[i]; o[n + i] = b[i]; o[2 * n + i] = c[i];
}

// ------------- transpose+convert: fp32 src [R][C] -> bf16 dst [C][R] -------
__global__ __launch_bounds__(256) void transpose_f32_bf16(const float* __restrict__ src,
                                                          u16* __restrict__ dst,
                                                          int R, int C) {
  __shared__ u16 tile[32][33];
  int tx = threadIdx.x & 31, ty = threadIdx.x >> 5;  // 32 x 8
  int c0 = blockIdx.x * 32, r0 = blockIdx.y * 32;
  #pragma unroll
  for (int i = ty; i < 32; i += 8)
    tile[i][tx] = f2bf(src[(size_t)(r0 + i) * C + c0 + tx]);
  __syncthreads();
  #pragma unroll
  for (int i = ty; i < 32; i += 8)
    dst[(size_t)(c0 + i) * R + r0 + tx] = tile[tx][i];
}

// ---- per-head V transpose from packed QKV: src row-stride RS, col offset CO ----
__global__ __launch_bounds__(256) void transpose_v(const u16* __restrict__ src,
                                                   u16* __restrict__ VT,
                                                   int B, int S, int H, int RS, int CO) {
  __shared__ u16 tile[32][33];
  int tx = threadIdx.x & 31, ty = threadIdx.x >> 5;
  int s0 = blockIdx.x * 32, d0 = blockIdx.y * 32;
  int bh = blockIdx.z;
  int b = bh / H, h = bh % H;
  #pragma unroll
  for (int i = ty; i < 32; i += 8)
    tile[i][tx] = src[(size_t)(b * S + s0 + i) * RS + CO + h * 64 + d0 + tx];
  __syncthreads();
  #pragma unroll
  for (int i = ty; i < 32; i += 8)
    VT[((size_t)bh * 64 + d0 + i) * S + s0 + tx] = tile[tx][i];
}

// ---------------- GEMM: C[M,N] = A[M,K] @ Bt[N,K]^T + bias, opt relu --------
// R9: BK=64 (halves barrier/drain events; 32 MFMA per barrier pair) + T2
//     source-swizzled staging: LDS[r][c] = M[r][c ^ ((r&7)<<3)], read with the
//     same XOR -> ds_read_b128 conflicts drop from 8/16-way to 2-way (free).
__global__ __launch_bounds__(256) void gemm_bt(const u16* __restrict__ A,
                                               const u16* __restrict__ Bt,
                                               const float* __restrict__ bias,
                                               u16* __restrict__ C,
                                               int M, int N, int K, int relu) {
  __shared__ u16 As[128 * 64];
  __shared__ u16 Bs[128 * 64];
  const int tid = threadIdx.x;
  const int lane = tid & 63, wid = tid >> 6;
  const int lr = lane & 15, quad = lane >> 4;
  const int wm = (wid >> 1) * 64, wn = (wid & 1) * 64;
  const int m0 = blockIdx.y * 128, n0 = blockIdx.x * 128;
  const int grow = lane >> 3;                    // row-within-8 (staging)
  const int gcol = ((lane & 7) ^ grow) * 8;      // pre-swizzled source col (u16)
  const int rsw = (lr & 7) << 3;                 // read-side swizzle (u16)

  f32x4 acc[4][4];
  const f32x4 zero = {0.f, 0.f, 0.f, 0.f};
  #pragma unroll
  for (int mt = 0; mt < 4; ++mt)
    #pragma unroll
    for (int nt = 0; nt < 4; ++nt) acc[mt][nt] = zero;

  for (int k0 = 0; k0 < K; k0 += 64) {
    #pragma unroll
    for (int it = 0; it < 4; ++it) {
      int rbase = wid * 32 + it * 8;
      gload_lds16(A + (size_t)(m0 + rbase + grow) * K + k0 + gcol, &As[rbase * 64]);
      gload_lds16(Bt + (size_t)(n0 + rbase + grow) * K + k0 + gcol, &Bs[rbase * 64]);
    }
    __syncthreads();
    #pragma unroll
    for (int kk = 0; kk < 2; ++kk) {
      bf16x8 af[4], bfr[4];
      #pragma unroll
      for (int mt = 0; mt < 4; ++mt)
        af[mt] = *(const bf16x8*)(&As[(wm + mt * 16 + lr) * 64 + ((kk * 32 + quad * 8) ^ rsw)]);
      #pragma unroll
      for (int nt = 0; nt < 4; ++nt)
        bfr[nt] = *(const bf16x8*)(&Bs[(wn + nt * 16 + lr) * 64 + ((kk * 32 + quad * 8) ^ rsw)]);
      #pragma unroll
      for (int mt = 0; mt < 4; ++mt)
        #pragma unroll
        for (int nt = 0; nt < 4; ++nt)
          acc[mt][nt] = __builtin_amdgcn_mfma_f32_16x16x32_bf16(af[mt], bfr[nt], acc[mt][nt], 0, 0, 0);
    }
    __syncthreads();
  }

  #pragma unroll
  for (int nt = 0; nt < 4; ++nt) {
    int n = n0 + wn + nt * 16 + lr;
    float bv = bias[n];
    #pragma unroll
    for (int mt = 0; mt < 4; ++mt) {
      #pragma unroll
      for (int i = 0; i < 4; ++i) {
        int m = m0 + wm + mt * 16 + quad * 4 + i;
        float v = acc[mt][nt][i] + bv;
        if (relu) v = fmaxf(v, 0.f);
        C[(size_t)m * N + n] = f2bf(v);
      }
    }
  }
}

// ---------------- flash attention (S^T, 32 q-rows per wave, 32x32 MFMA) -----
// R9: 2-wave/64-q blocks (grid 2048 = 8 blocks/CU; barriers span 2 waves;
//     8 independent blocks/CU cover each other's staging drains) + XCD-
//     clustered 1D grid: bh = (bid&7)*8 + ((bid>>3)&7), qb = bid>>6 -> each
//     XCD owns 8 heads, working set 8x512KB = 4MB = its L2. Datapath = R3's
//     verified 32x32 path (in-register P redistribution, ballot mask,
//     raw-domain defer-max).
__global__ __launch_bounds__(128) void flash_attn(const u16* __restrict__ Qp,
                                                  const u16* __restrict__ Kp,
                                                  const u16* __restrict__ VT,
                                                  const int* __restrict__ mask,
                                                  u16* __restrict__ ctx,
                                                  int B, int S, int H, int QSTR) {
  __shared__ u16 kt_lds[64 * 64];        // K tile [k][d], linear; XOR-swizzled data
  __shared__ u16 vt_lds[64 * 64];        // V^T tile [d][k], linear; XOR-swizzled data
  const int tid = threadIdx.x;
  const int lane = tid & 63, wid = tid >> 6;   // wid in {0,1}
  const int l31 = lane & 31, hi = lane >> 5;
  const int bid = blockIdx.x;
  const int bh = (bid & 7) * 8 + ((bid >> 3) & 7);   // XCD-clustered heads
  const int qb = bid >> 6;
  const int b = bh / H, h = bh % H;
  const u16* vt_base = VT + (size_t)bh * 64 * S;
  const int* mbase = mask + b * S;
  const float SC = 0.125f * 1.44269504089f;   // 1/sqrt(dk) * log2(e)

  // staging: each wave stages rows [wid*32, wid*32+32) of K and V^T.
  // LDS dest linear; global source col pre-swizzled so LDS[r][c] = M[r][c ^ ((r&7)<<3)].
  const int srl = lane >> 3;                         // row-within-8
  const int scol = ((lane & 7) ^ srl) * 8;           // pre-swizzled source col (u16)
  const int rsw = (lane & 7) << 3;                   // read-side swizzle (row&7 == lane&7)

  // Q fragments: B-operand, q = qb*64 + wid*32 + l31, k-chunk by hi bit
  const int q = qb * 64 + wid * 32 + l31;
  bf16x8 qf[4];
  {
    const u16* qptr = Qp + (size_t)(b * S + q) * QSTR + h * 64;
    #pragma unroll
    for (int t = 0; t < 4; ++t)
      qf[t] = *(const bf16x8*)(qptr + t * 16 + hi * 8);
  }

  float m_i = -1e30f, l_i = 0.f;        // per-lane partials (pair-reduced at end)
  f32x16 o0 = zero16(), o1 = zero16();  // O^T: d-half 0 / 1

  const u16* kgp = Kp + ((size_t)b * S + wid * 32 + srl) * QSTR + h * 64 + scol;
  const u16* vgp = vt_base + (size_t)(wid * 32 + srl) * S + scol;
  u16* klb = &kt_lds[(wid * 32) * 64];
  u16* vlb = &vt_lds[(wid * 32) * 64];

  for (int kt = 0; kt < S; kt += 64) {
    #pragma unroll
    for (int it = 0; it < 4; ++it) {
      gload_lds16(kgp + (size_t)(kt + it * 8) * QSTR, klb + it * 8 * 64);
      gload_lds16(vgp + (size_t)(it * 8) * S + kt, vlb + it * 8 * 64);
    }
    int mv = mbase[kt + lane];
    unsigned long long bal = __ballot(mv != 0);
    __syncthreads();

    // ---- S^T = K @ Q^T (raw domain): col = q = l31, row = k via reg pattern
    f32x16 sa0 = zero16(), sa1 = zero16();
    const u16* krow0 = &kt_lds[l31 * 64];
    const u16* krow1 = &kt_lds[(32 + l31) * 64];
    __builtin_amdgcn_s_setprio(1);
    #pragma unroll
    for (int dblock = 0; dblock < 4; ++dblock) {
      int c = (dblock * 16 + hi * 8) ^ rsw;
      bf16x8 kf0 = *(const bf16x8*)(krow0 + c);
      bf16x8 kf1 = *(const bf16x8*)(krow1 + c);
      sa0 = __builtin_amdgcn_mfma_f32_32x32x16_bf16(kf0, qf[dblock], sa0, 0, 0, 0);
      sa1 = __builtin_amdgcn_mfma_f32_32x32x16_bf16(kf1, qf[dblock], sa1, 0, 0, 0);
    }
    __builtin_amdgcn_s_setprio(0);

    // ---- mask (rare path; benchmark mask is all-ones -> skipped entirely)
    if (bal != 0xFFFFFFFFFFFFFFFFull) {
      unsigned long long balh = bal >> (hi * 4);
      #pragma unroll
      for (int r = 0; r < 16; ++r) {
        int kloc = (r & 3) + 8 * (r >> 2);
        if (!((balh >> kloc) & 1)) sa0[r] = -2e30f;
        if (!((balh >> (32 + kloc)) & 1)) sa1[r] = -2e30f;
      }
    }

    // ---- online softmax, defer-max (raw-domain THR = 44 ~ exp2(8) P bound)
    float tmax = sa0[0];
    #pragma unroll
    for (int r = 1; r < 16; ++r) tmax = fmaxf(tmax, sa0[r]);
    #pragma unroll
    for (int r = 0; r < 16; ++r) tmax = fmaxf(tmax, sa1[r]);
    tmax = fmaxf(tmax, __shfl_xor(tmax, 32, 64));
    if (__any(tmax > m_i + 44.0f)) {
      float mn = fmaxf(m_i, tmax);
      float al = exp2f((m_i - mn) * SC);
      m_i = mn;
      l_i *= al;
      #pragma unroll
      for (int r = 0; r < 16; ++r) { o0[r] *= al; o1[r] *= al; }
    }
    float msc = m_i * SC;
    float rs = 0.f;
    #pragma unroll
    for (int r = 0; r < 16; ++r) {
      float p0 = exp2f(__builtin_fmaf(sa0[r], SC, -msc));
      float p1 = exp2f(__builtin_fmaf(sa1[r], SC, -msc));
      sa0[r] = p0; sa1[r] = p1; rs += p0 + p1;
    }
    l_i += rs;

    // ---- P -> bf16 + pair redistribution fully in registers.
    unsigned pfw[4][4];
    #pragma unroll
    for (int b1 = 0; b1 < 2; ++b1) {
      #pragma unroll
      for (int pair = 0; pair < 2; ++pair) {
        unsigned X0 = cvt_pk_bf16(sa0[(2 * b1) * 4 + pair * 2], sa0[(2 * b1) * 4 + pair * 2 + 1]);
        unsigned Y0 = cvt_pk_bf16(sa0[(2 * b1 + 1) * 4 + pair * 2], sa0[(2 * b1 + 1) * 4 + pair * 2 + 1]);
        unsigned Xp0 = __shfl_xor(X0, 32, 64);
        unsigned Yp0 = __shfl_xor(Y0, 32, 64);
        pfw[b1][pair] = hi ? Yp0 : X0;
        pfw[b1][pair + 2] = hi ? Y0 : Xp0;
        unsigned X1 = cvt_pk_bf16(sa1[(2 * b1) * 4 + pair * 2], sa1[(2 * b1) * 4 + pair * 2 + 1]);
        unsigned Y1 = cvt_pk_bf16(sa1[(2 * b1 + 1) * 4 + pair * 2], sa1[(2 * b1 + 1) * 4 + pair * 2 + 1]);
        unsigned Xp1 = __shfl_xor(X1, 32, 64);
        unsigned Yp1 = __shfl_xor(Y1, 32, 64);
        pfw[2 + b1][pair] = hi ? Yp1 : X1;
        pfw[2 + b1][pair + 2] = hi ? Y1 : Xp1;
      }
    }

    // ---- O^T += V^T @ P^T
    const u16* vrow0 = &vt_lds[l31 * 64];
    const u16* vrow1 = &vt_lds[(32 + l31) * 64];
    __builtin_amdgcn_s_setprio(1);
    #pragma unroll
    for (int kb = 0; kb < 4; ++kb) {
      int c = (kb * 16 + hi * 8) ^ rsw;
      bf16x8 vf0 = *(const bf16x8*)(vrow0 + c);
      bf16x8 vf1 = *(const bf16x8*)(vrow1 + c);
      union { unsigned w[4]; bf16x8 v; } pu;
      pu.w[0] = pfw[kb][0]; pu.w[1] = pfw[kb][1];
      pu.w[2] = pfw[kb][2]; pu.w[3] = pfw[kb][3];
      o0 = __builtin_amdgcn_mfma_f32_32x32x16_bf16(vf0, pu.v, o0, 0, 0, 0);
      o1 = __builtin_amdgcn_mfma_f32_32x32x16_bf16(vf1, pu.v, o1, 0, 0, 0);
    }
    __builtin_amdgcn_s_setprio(0);
    __syncthreads();
  }

  // epilogue: finish l over the lane pair; d = 8*rq + 4*hi + i (+32 for o1)
  l_i += __shfl_xor(l_i, 32, 64);
  float linv = 1.f / fmaxf(l_i, 1e-30f);
  u16* op = ctx + (size_t)(b * S + q) * (H * 64) + h * 64;
  #pragma unroll
  for (int rq = 0; rq < 4; ++rq) {
    uint2 w0, w1;
    w0.x = cvt_pk_bf16(o0[rq * 4 + 0] * linv, o0[rq * 4 + 1] * linv);
    w0.y = cvt_pk_bf16(o0[rq * 4 + 2] * linv, o0[rq * 4 + 3] * linv);
    *(uint2*)(op + rq * 8 + hi * 4) = w0;
    w1.x = cvt_pk_bf16(o1[rq * 4 + 0] * linv, o1[rq * 4 + 1] * linv);
    w1.y = cvt_pk_bf16(o1[rq * 4 + 2] * linv, o1[rq * 4 + 3] * linv);
    *(uint2*)(op + 32 + rq * 8 + hi * 4) = w1;
  }
}

// ---------------- fused residual add + LayerNorm (vectorized) ----------------
__device__ inline float block_reduce_sum(float v, float* sbuf) {
  #pragma unroll
  for (int m = 1; m < 64; m <<= 1) v += __shfl_xor(v, m, 64);
  int w = threadIdx.x >> 6;
  if ((threadIdx.x & 63) == 0) sbuf[w] = v;
  __syncthreads();
  v = sbuf[0] + sbuf[1] + sbuf[2] + sbuf[3];
  __syncthreads();
  return v;
}

__global__ __launch_bounds__(256) void add_ln(const float* __restrict__ a32,
                                              const u16* __restrict__ a16,
                                              const u16* __restrict__ b,
                                              const float* __restrict__ g,
                                              const float* __restrict__ be,
                                              u16* __restrict__ out16,
                                              float* __restrict__ out32, int D) {
  __shared__ float sbuf[4];
  int row = blockIdx.x;
  size_t base = (size_t)row * D;
  int i = threadIdx.x * 4;
  float v[4];
  {
    u16x4 bv = *(const u16x4*)(b + base + i);
    if (a32) {
      float4 av = *(const float4*)(a32 + base + i);
      v[0] = av.x + bf2f(bv.x); v[1] = av.y + bf2f(bv.y);
      v[2] = av.z + bf2f(bv.z); v[3] = av.w + bf2f(bv.w);
    } else {
      u16x4 av = *(const u16x4*)(a16 + base + i);
      v[0] = bf2f(av.x) + bf2f(bv.x); v[1] = bf2f(av.y) + bf2f(bv.y);
      v[2] = bf2f(av.z) + bf2f(bv.z); v[3] = bf2f(av.w) + bf2f(bv.w);
    }
  }
  float sum = v[0] + v[1] + v[2] + v[3];
  sum = block_reduce_sum(sum, sbuf);
  float mean = sum / (float)D;
  float var = 0.f;
  #pragma unroll
  for (int j = 0; j < 4; ++j) { float d = v[j] - mean; var += d * d; }
  var = block_reduce_sum(var, sbuf);
  float rstd = rsqrtf(var / (float)D + 1e-5f);
  float4 gv = *(const float4*)(g + i);
  float4 bev = *(const float4*)(be + i);
  float o0 = (v[0] - mean) * rstd * gv.x + bev.x;
  float o1 = (v[1] - mean) * rstd * gv.y + bev.y;
  float o2 = (v[2] - mean) * rstd * gv.z + bev.z;
  float o3 = (v[3] - mean) * rstd * gv.w + bev.w;
  if (out32) {
    float4 o = {o0, o1, o2, o3};
    *(float4*)(out32 + base + i) = o;
  } else {
    u16x4 o;
    o.x = f2bf(o0); o.y = f2bf(o1); o.z = f2bf(o2); o.w = f2bf(o3);
    *(u16x4*)(out16 + base + i) = o;
  }
}

// ---------------- launch ----------------
extern "C" void kernel_launch(void* const* d_in, const int* in_sizes, int n_in,
                              void* d_out, int out_size, void* d_ws, size_t ws_size,
                              hipStream_t stream) {
  (void)in_sizes; (void)n_in; (void)out_size; (void)ws_size;
  const float* x   = (const float*)d_in[0];
  const int* mask  = (const int*)d_in[1];
  const float* wq  = (const float*)d_in[2];
  const float* bq  = (const float*)d_in[3];
  const float* wk  = (const float*)d_in[4];
  const float* bk  = (const float*)d_in[5];
  const float* wv  = (const float*)d_in[6];
  const float* bv  = (const float*)d_in[7];
  const float* wo  = (const float*)d_in[8];
  const float* bo  = (const float*)d_in[9];
  const float* w1  = (const float*)d_in[10];
  const float* b1  = (const float*)d_in[11];
  const float* w2  = (const float*)d_in[12];
  const float* b2  = (const float*)d_in[13];
  const float* g1  = (const float*)d_in[14];
  const float* be1 = (const float*)d_in[15];
  const float* g2  = (const float*)d_in[16];
  const float* be2 = (const float*)d_in[17];

  const int B = 4, S = 2048, D = 1024, H = 16, DFF = 4096;
  const int D3 = 3 * D;
  const size_t TOK = (size_t)B * S;
  const size_t TD = TOK * D;

  u16* ws   = (u16*)d_ws;
  u16* QKVp = ws;                          // [0, 3*TD)
  u16* xb   = ws + 3 * TD;                 // dead after QKV gemm
  u16* VT   = xb;
  u16* CTX  = ws + 4 * TD;
  u16* ATT  = ws + 5 * TD;
  u16* Hb   = ws + 6 * TD;
  u16* QKVT = ws + 7 * TD;                 // 3*D*D
  u16* WOT  = QKVT + 3 * (size_t)D * D;    // D*D
  u16* W1T  = WOT + (size_t)D * D;         // D*DFF
  u16* FF1  = ws;                          // overlays QKVp+VT
  u16* FF2  = ATT;
  u16* W2T  = QKVT;                        // into dead QKVT+WOT
  float* biasc = (float*)CTX;              // dead before flash writes CTX

  dim3 blk(256);

  cvt_bf16<<<dim3((unsigned)(TD / (256 * 4))), blk, 0, stream>>>(x, xb, (int)TD);
  concat3<<<dim3(4), blk, 0, stream>>>(bq, bk, bv, biasc, D);

  transpose_f32_bf16<<<dim3(D / 32, D / 32), blk, 0, stream>>>(wq, QKVT, D, D);
  transpose_f32_bf16<<<dim3(D / 32, D / 32), blk, 0, stream>>>(wk, QKVT + (size_t)D * D, D, D);
  transpose_f32_bf16<<<dim3(D / 32, D / 32), blk, 0, stream>>>(wv, QKVT + 2 * (size_t)D * D, D, D);
  transpose_f32_bf16<<<dim3(D / 32, D / 32), blk, 0, stream>>>(wo, WOT, D, D);
  transpose_f32_bf16<<<dim3(DFF / 32, D / 32), blk, 0, stream>>>(w1, W1T, D, DFF);

  gemm_bt<<<dim3(D3 / 128, TOK / 128), blk, 0, stream>>>(xb, QKVT, biasc, QKVp, (int)TOK, D3, D, 0);

  transpose_v<<<dim3(S / 32, 2, B * H), blk, 0, stream>>>(QKVp, VT, B, S, H, D3, 2 * D);

  flash_attn<<<dim3((unsigned)((S / 64) * B * H)), dim3(128), 0, stream>>>(
      QKVp, QKVp + D, VT, mask, CTX, B, S, H, D3);

  gemm_bt<<<dim3(D / 128, TOK / 128), blk, 0, stream>>>(CTX, WOT, bo, ATT, (int)TOK, D, D, 0);

  transpose_f32_bf16<<<dim3(D / 32, DFF / 32), blk, 0, stream>>>(w2, W2T, DFF, D);

  add_ln<<<dim3((unsigned)TOK), blk, 0, stream>>>(x, (const u16*)nullptr, ATT, g1, be1,
                                                  Hb, (float*)nullptr, D);

  gemm_bt<<<dim3(DFF / 128, TOK / 128), blk, 0, stream>>>(Hb, W1T, b1, FF1, (int)TOK, DFF, D, 1);
  gemm_bt<<<dim3(D / 128, TOK / 128), blk, 0, stream>>>(FF1, W2T, b2, FF2, (int)TOK, D, DFF, 0);

  add_ln<<<dim3((unsigned)TOK), blk, 0, stream>>>((const float*)nullptr, Hb, FF2, g2, be2,
                                                  (u16*)nullptr, (float*)d_out, D);
}

// Round 5
// 642.800 us; speedup vs baseline: 1.0827x; 1.0112x over previous
//
#include <hip/hip_runtime.h>

typedef unsigned short u16;
typedef __attribute__((ext_vector_type(4))) unsigned short u16x4;
typedef __attribute__((ext_vector_type(8))) short bf16x8;
typedef __attribute__((ext_vector_type(4))) float f32x4;
typedef __attribute__((ext_vector_type(16))) float f32x16;

__device__ inline float bf2f(u16 u) {
  union { unsigned int i; float f; } v; v.i = ((unsigned int)u) << 16; return v.f;
}
__device__ inline u16 f2bf(float f) {
  union { float f; unsigned int i; } v; v.f = f;
  unsigned int r = v.i + 0x7fffu + ((v.i >> 16) & 1u);
  return (u16)(r >> 16);
}
// single-instruction pack of two f32 -> 2xbf16 (T12 primitive; no builtin on gfx950)
__device__ inline unsigned int cvt_pk_bf16(float lo, float hi) {
  unsigned int r;
  asm("v_cvt_pk_bf16_f32 %0, %1, %2" : "=v"(r) : "v"(lo), "v"(hi));
  return r;
}
__device__ inline f32x16 zero16() {
  f32x16 z;
  #pragma unroll
  for (int i = 0; i < 16; ++i) z[i] = 0.f;
  return z;
}

// async global->LDS, 16B per lane; LDS dest = wave-uniform base + lane*16 (m97/m104)
typedef const __attribute__((address_space(1))) unsigned int* gas_t;
typedef __attribute__((address_space(3))) unsigned int* las_t;
__device__ inline void gload_lds16(const u16* g, u16* l) {
  __builtin_amdgcn_global_load_lds((gas_t)(unsigned long long)(const void*)g,
                                   (las_t)(unsigned int)(unsigned long long)(void*)l,
                                   16, 0, 0);
}

// ---------------- fp32 -> bf16 convert (x) ----------------
__global__ __launch_bounds__(256) void cvt_bf16(const float* __restrict__ src,
                                                u16* __restrict__ dst, int n) {
  int i = (blockIdx.x * 256 + threadIdx.x) * 4;
  if (i >= n) return;
  float4 v = *(const float4*)(src + i);
  u16x4 o;
  o.x = f2bf(v.x); o.y = f2bf(v.y); o.z = f2bf(v.z); o.w = f2bf(v.w);
  *(u16x4*)(dst + i) = o;
}

// ---------------- bias concat (fp32): [bq|bk|bv] -> o[3n] ----------------
__global__ __launch_bounds__(256) void concat3(const float* __restrict__ a,
                                               const float* __restrict__ b,
                                               const float* __restrict__ c,
                                               float* __restrict__ o, int n) {
  int i = blockIdx.x * 256 + threadIdx.x;
  if (i >= n) return;
  o[i] = a[i]; o[n + i] = b[i]; o[2 * n + i] = c[i];
}

// ------------- transpose+convert: fp32 src [R][C] -> bf16 dst [C][R] -------
__global__ __launch_bounds__(256) void transpose_f32_bf16(const float* __restrict__ src,
                                                          u16* __restrict__ dst,
                                                          int R, int C) {
  __shared__ u16 tile[32][33];
  int tx = threadIdx.x & 31, ty = threadIdx.x >> 5;  // 32 x 8
  int c0 = blockIdx.x * 32, r0 = blockIdx.y * 32;
  #pragma unroll
  for (int i = ty; i < 32; i += 8)
    tile[i][tx] = f2bf(src[(size_t)(r0 + i) * C + c0 + tx]);
  __syncthreads();
  #pragma unroll
  for (int i = ty; i < 32; i += 8)
    dst[(size_t)(c0 + i) * R + r0 + tx] = tile[tx][i];
}

// ---- per-head V transpose from packed QKV: src row-stride RS, col offset CO ----
__global__ __launch_bounds__(256) void transpose_v(const u16* __restrict__ src,
                                                   u16* __restrict__ VT,
                                                   int B, int S, int H, int RS, int CO) {
  __shared__ u16 tile[32][33];
  int tx = threadIdx.x & 31, ty = threadIdx.x >> 5;
  int s0 = blockIdx.x * 32, d0 = blockIdx.y * 32;
  int bh = blockIdx.z;
  int b = bh / H, h = bh % H;
  #pragma unroll
  for (int i = ty; i < 32; i += 8)
    tile[i][tx] = src[(size_t)(b * S + s0 + i) * RS + CO + h * 64 + d0 + tx];
  __syncthreads();
  #pragma unroll
  for (int i = ty; i < 32; i += 8)
    VT[((size_t)bh * 64 + d0 + i) * S + s0 + tx] = tile[tx][i];
}

// ---------------- GEMM: C[M,N] = A[M,K] @ Bt[N,K]^T + bias, opt relu --------
// R9: BK=64 (halves barrier/drain events; 32 MFMA per barrier pair) + T2
//     source-swizzled staging: LDS[r][c] = M[r][c ^ ((r&7)<<3)], read with the
//     same XOR -> ds_read_b128 conflicts drop from 8/16-way to 2-way (free).
__global__ __launch_bounds__(256) void gemm_bt(const u16* __restrict__ A,
                                               const u16* __restrict__ Bt,
                                               const float* __restrict__ bias,
                                               u16* __restrict__ C,
                                               int M, int N, int K, int relu) {
  __shared__ u16 As[128 * 64];
  __shared__ u16 Bs[128 * 64];
  const int tid = threadIdx.x;
  const int lane = tid & 63, wid = tid >> 6;
  const int lr = lane & 15, quad = lane >> 4;
  const int wm = (wid >> 1) * 64, wn = (wid & 1) * 64;
  const int m0 = blockIdx.y * 128, n0 = blockIdx.x * 128;
  const int grow = lane >> 3;                    // row-within-8 (staging)
  const int gcol = ((lane & 7) ^ grow) * 8;      // pre-swizzled source col (u16)
  const int rsw = (lr & 7) << 3;                 // read-side swizzle (u16)

  f32x4 acc[4][4];
  const f32x4 zero = {0.f, 0.f, 0.f, 0.f};
  #pragma unroll
  for (int mt = 0; mt < 4; ++mt)
    #pragma unroll
    for (int nt = 0; nt < 4; ++nt) acc[mt][nt] = zero;

  for (int k0 = 0; k0 < K; k0 += 64) {
    #pragma unroll
    for (int it = 0; it < 4; ++it) {
      int rbase = wid * 32 + it * 8;
      gload_lds16(A + (size_t)(m0 + rbase + grow) * K + k0 + gcol, &As[rbase * 64]);
      gload_lds16(Bt + (size_t)(n0 + rbase + grow) * K + k0 + gcol, &Bs[rbase * 64]);
    }
    __syncthreads();
    #pragma unroll
    for (int kk = 0; kk < 2; ++kk) {
      bf16x8 af[4], bfr[4];
      #pragma unroll
      for (int mt = 0; mt < 4; ++mt)
        af[mt] = *(const bf16x8*)(&As[(wm + mt * 16 + lr) * 64 + ((kk * 32 + quad * 8) ^ rsw)]);
      #pragma unroll
      for (int nt = 0; nt < 4; ++nt)
        bfr[nt] = *(const bf16x8*)(&Bs[(wn + nt * 16 + lr) * 64 + ((kk * 32 + quad * 8) ^ rsw)]);
      #pragma unroll
      for (int mt = 0; mt < 4; ++mt)
        #pragma unroll
        for (int nt = 0; nt < 4; ++nt)
          acc[mt][nt] = __builtin_amdgcn_mfma_f32_16x16x32_bf16(af[mt], bfr[nt], acc[mt][nt], 0, 0, 0);
    }
    __syncthreads();
  }

  #pragma unroll
  for (int nt = 0; nt < 4; ++nt) {
    int n = n0 + wn + nt * 16 + lr;
    float bv = bias[n];
    #pragma unroll
    for (int mt = 0; mt < 4; ++mt) {
      #pragma unroll
      for (int i = 0; i < 4; ++i) {
        int m = m0 + wm + mt * 16 + quad * 4 + i;
        float v = acc[mt][nt][i] + bv;
        if (relu) v = fmaxf(v, 0.f);
        C[(size_t)m * N + n] = f2bf(v);
      }
    }
  }
}

// ---------------- flash attention (S^T, 32 q-rows per wave, 32x32 MFMA) -----
// R10: isolate R4's regression — keep the 2-wave/64-q blocks (grid 2048 =
//      8 blocks/CU x 2 waves = 16 waves/CU static ceiling at VGPR~100) but
//      DROP the XCD head remap: natural 2D grid (S/64, B*H); consecutive
//      blocks share (b,h) K/V -> L2 locality the natural way. Datapath =
//      R3's verified 32x32 path (in-register P redistribution, ballot mask,
//      raw-domain defer-max).
__global__ __launch_bounds__(128) void flash_attn(const u16* __restrict__ Qp,
                                                  const u16* __restrict__ Kp,
                                                  const u16* __restrict__ VT,
                                                  const int* __restrict__ mask,
                                                  u16* __restrict__ ctx,
                                                  int B, int S, int H, int QSTR) {
  __shared__ u16 kt_lds[64 * 64];        // K tile [k][d], linear; XOR-swizzled data
  __shared__ u16 vt_lds[64 * 64];        // V^T tile [d][k], linear; XOR-swizzled data
  const int tid = threadIdx.x;
  const int lane = tid & 63, wid = tid >> 6;   // wid in {0,1}
  const int l31 = lane & 31, hi = lane >> 5;
  const int bh = blockIdx.y;
  const int qb = blockIdx.x;
  const int b = bh / H, h = bh % H;
  const u16* vt_base = VT + (size_t)bh * 64 * S;
  const int* mbase = mask + b * S;
  const float SC = 0.125f * 1.44269504089f;   // 1/sqrt(dk) * log2(e)

  // staging: each wave stages rows [wid*32, wid*32+32) of K and V^T.
  // LDS dest linear; global source col pre-swizzled so LDS[r][c] = M[r][c ^ ((r&7)<<3)].
  const int srl = lane >> 3;                         // row-within-8
  const int scol = ((lane & 7) ^ srl) * 8;           // pre-swizzled source col (u16)
  const int rsw = (lane & 7) << 3;                   // read-side swizzle (row&7 == lane&7)

  // Q fragments: B-operand, q = qb*64 + wid*32 + l31, k-chunk by hi bit
  const int q = qb * 64 + wid * 32 + l31;
  bf16x8 qf[4];
  {
    const u16* qptr = Qp + (size_t)(b * S + q) * QSTR + h * 64;
    #pragma unroll
    for (int t = 0; t < 4; ++t)
      qf[t] = *(const bf16x8*)(qptr + t * 16 + hi * 8);
  }

  float m_i = -1e30f, l_i = 0.f;        // per-lane partials (pair-reduced at end)
  f32x16 o0 = zero16(), o1 = zero16();  // O^T: d-half 0 / 1

  const u16* kgp = Kp + ((size_t)b * S + wid * 32 + srl) * QSTR + h * 64 + scol;
  const u16* vgp = vt_base + (size_t)(wid * 32 + srl) * S + scol;
  u16* klb = &kt_lds[(wid * 32) * 64];
  u16* vlb = &vt_lds[(wid * 32) * 64];

  for (int kt = 0; kt < S; kt += 64) {
    #pragma unroll
    for (int it = 0; it < 4; ++it) {
      gload_lds16(kgp + (size_t)(kt + it * 8) * QSTR, klb + it * 8 * 64);
      gload_lds16(vgp + (size_t)(it * 8) * S + kt, vlb + it * 8 * 64);
    }
    int mv = mbase[kt + lane];
    unsigned long long bal = __ballot(mv != 0);
    __syncthreads();

    // ---- S^T = K @ Q^T (raw domain): col = q = l31, row = k via reg pattern
    f32x16 sa0 = zero16(), sa1 = zero16();
    const u16* krow0 = &kt_lds[l31 * 64];
    const u16* krow1 = &kt_lds[(32 + l31) * 64];
    __builtin_amdgcn_s_setprio(1);
    #pragma unroll
    for (int dblock = 0; dblock < 4; ++dblock) {
      int c = (dblock * 16 + hi * 8) ^ rsw;
      bf16x8 kf0 = *(const bf16x8*)(krow0 + c);
      bf16x8 kf1 = *(const bf16x8*)(krow1 + c);
      sa0 = __builtin_amdgcn_mfma_f32_32x32x16_bf16(kf0, qf[dblock], sa0, 0, 0, 0);
      sa1 = __builtin_amdgcn_mfma_f32_32x32x16_bf16(kf1, qf[dblock], sa1, 0, 0, 0);
    }
    __builtin_amdgcn_s_setprio(0);

    // ---- mask (rare path; benchmark mask is all-ones -> skipped entirely)
    if (bal != 0xFFFFFFFFFFFFFFFFull) {
      unsigned long long balh = bal >> (hi * 4);
      #pragma unroll
      for (int r = 0; r < 16; ++r) {
        int kloc = (r & 3) + 8 * (r >> 2);
        if (!((balh >> kloc) & 1)) sa0[r] = -2e30f;
        if (!((balh >> (32 + kloc)) & 1)) sa1[r] = -2e30f;
      }
    }

    // ---- online softmax, defer-max (raw-domain THR = 44 ~ exp2(8) P bound)
    float tmax = sa0[0];
    #pragma unroll
    for (int r = 1; r < 16; ++r) tmax = fmaxf(tmax, sa0[r]);
    #pragma unroll
    for (int r = 0; r < 16; ++r) tmax = fmaxf(tmax, sa1[r]);
    tmax = fmaxf(tmax, __shfl_xor(tmax, 32, 64));
    if (__any(tmax > m_i + 44.0f)) {
      float mn = fmaxf(m_i, tmax);
      float al = exp2f((m_i - mn) * SC);
      m_i = mn;
      l_i *= al;
      #pragma unroll
      for (int r = 0; r < 16; ++r) { o0[r] *= al; o1[r] *= al; }
    }
    float msc = m_i * SC;
    float rs = 0.f;
    #pragma unroll
    for (int r = 0; r < 16; ++r) {
      float p0 = exp2f(__builtin_fmaf(sa0[r], SC, -msc));
      float p1 = exp2f(__builtin_fmaf(sa1[r], SC, -msc));
      sa0[r] = p0; sa1[r] = p1; rs += p0 + p1;
    }
    l_i += rs;

    // ---- P -> bf16 + pair redistribution fully in registers.
    unsigned pfw[4][4];
    #pragma unroll
    for (int b1 = 0; b1 < 2; ++b1) {
      #pragma unroll
      for (int pair = 0; pair < 2; ++pair) {
        unsigned X0 = cvt_pk_bf16(sa0[(2 * b1) * 4 + pair * 2], sa0[(2 * b1) * 4 + pair * 2 + 1]);
        unsigned Y0 = cvt_pk_bf16(sa0[(2 * b1 + 1) * 4 + pair * 2], sa0[(2 * b1 + 1) * 4 + pair * 2 + 1]);
        unsigned Xp0 = __shfl_xor(X0, 32, 64);
        unsigned Yp0 = __shfl_xor(Y0, 32, 64);
        pfw[b1][pair] = hi ? Yp0 : X0;
        pfw[b1][pair + 2] = hi ? Y0 : Xp0;
        unsigned X1 = cvt_pk_bf16(sa1[(2 * b1) * 4 + pair * 2], sa1[(2 * b1) * 4 + pair * 2 + 1]);
        unsigned Y1 = cvt_pk_bf16(sa1[(2 * b1 + 1) * 4 + pair * 2], sa1[(2 * b1 + 1) * 4 + pair * 2 + 1]);
        unsigned Xp1 = __shfl_xor(X1, 32, 64);
        unsigned Yp1 = __shfl_xor(Y1, 32, 64);
        pfw[2 + b1][pair] = hi ? Yp1 : X1;
        pfw[2 + b1][pair + 2] = hi ? Y1 : Xp1;
      }
    }

    // ---- O^T += V^T @ P^T
    const u16* vrow0 = &vt_lds[l31 * 64];
    const u16* vrow1 = &vt_lds[(32 + l31) * 64];
    __builtin_amdgcn_s_setprio(1);
    #pragma unroll
    for (int kb = 0; kb < 4; ++kb) {
      int c = (kb * 16 + hi * 8) ^ rsw;
      bf16x8 vf0 = *(const bf16x8*)(vrow0 + c);
      bf16x8 vf1 = *(const bf16x8*)(vrow1 + c);
      union { unsigned w[4]; bf16x8 v; } pu;
      pu.w[0] = pfw[kb][0]; pu.w[1] = pfw[kb][1];
      pu.w[2] = pfw[kb][2]; pu.w[3] = pfw[kb][3];
      o0 = __builtin_amdgcn_mfma_f32_32x32x16_bf16(vf0, pu.v, o0, 0, 0, 0);
      o1 = __builtin_amdgcn_mfma_f32_32x32x16_bf16(vf1, pu.v, o1, 0, 0, 0);
    }
    __builtin_amdgcn_s_setprio(0);
    __syncthreads();
  }

  // epilogue: finish l over the lane pair; d = 8*rq + 4*hi + i (+32 for o1)
  l_i += __shfl_xor(l_i, 32, 64);
  float linv = 1.f / fmaxf(l_i, 1e-30f);
  u16* op = ctx + (size_t)(b * S + q) * (H * 64) + h * 64;
  #pragma unroll
  for (int rq = 0; rq < 4; ++rq) {
    uint2 w0, w1;
    w0.x = cvt_pk_bf16(o0[rq * 4 + 0] * linv, o0[rq * 4 + 1] * linv);
    w0.y = cvt_pk_bf16(o0[rq * 4 + 2] * linv, o0[rq * 4 + 3] * linv);
    *(uint2*)(op + rq * 8 + hi * 4) = w0;
    w1.x = cvt_pk_bf16(o1[rq * 4 + 0] * linv, o1[rq * 4 + 1] * linv);
    w1.y = cvt_pk_bf16(o1[rq * 4 + 2] * linv, o1[rq * 4 + 3] * linv);
    *(uint2*)(op + 32 + rq * 8 + hi * 4) = w1;
  }
}

// ---------------- fused residual add + LayerNorm (vectorized) ----------------
__device__ inline float block_reduce_sum(float v, float* sbuf) {
  #pragma unroll
  for (int m = 1; m < 64; m <<= 1) v += __shfl_xor(v, m, 64);
  int w = threadIdx.x >> 6;
  if ((threadIdx.x & 63) == 0) sbuf[w] = v;
  __syncthreads();
  v = sbuf[0] + sbuf[1] + sbuf[2] + sbuf[3];
  __syncthreads();
  return v;
}

__global__ __launch_bounds__(256) void add_ln(const float* __restrict__ a32,
                                              const u16* __restrict__ a16,
                                              const u16* __restrict__ b,
                                              const float* __restrict__ g,
                                              const float* __restrict__ be,
                                              u16* __restrict__ out16,
                                              float* __restrict__ out32, int D) {
  __shared__ float sbuf[4];
  int row = blockIdx.x;
  size_t base = (size_t)row * D;
  int i = threadIdx.x * 4;
  float v[4];
  {
    u16x4 bv = *(const u16x4*)(b + base + i);
    if (a32) {
      float4 av = *(const float4*)(a32 + base + i);
      v[0] = av.x + bf2f(bv.x); v[1] = av.y + bf2f(bv.y);
      v[2] = av.z + bf2f(bv.z); v[3] = av.w + bf2f(bv.w);
    } else {
      u16x4 av = *(const u16x4*)(a16 + base + i);
      v[0] = bf2f(av.x) + bf2f(bv.x); v[1] = bf2f(av.y) + bf2f(bv.y);
      v[2] = bf2f(av.z) + bf2f(bv.z); v[3] = bf2f(av.w) + bf2f(bv.w);
    }
  }
  float sum = v[0] + v[1] + v[2] + v[3];
  sum = block_reduce_sum(sum, sbuf);
  float mean = sum / (float)D;
  float var = 0.f;
  #pragma unroll
  for (int j = 0; j < 4; ++j) { float d = v[j] - mean; var += d * d; }
  var = block_reduce_sum(var, sbuf);
  float rstd = rsqrtf(var / (float)D + 1e-5f);
  float4 gv = *(const float4*)(g + i);
  float4 bev = *(const float4*)(be + i);
  float o0 = (v[0] - mean) * rstd * gv.x + bev.x;
  float o1 = (v[1] - mean) * rstd * gv.y + bev.y;
  float o2 = (v[2] - mean) * rstd * gv.z + bev.z;
  float o3 = (v[3] - mean) * rstd * gv.w + bev.w;
  if (out32) {
    float4 o = {o0, o1, o2, o3};
    *(float4*)(out32 + base + i) = o;
  } else {
    u16x4 o;
    o.x = f2bf(o0); o.y = f2bf(o1); o.z = f2bf(o2); o.w = f2bf(o3);
    *(u16x4*)(out16 + base + i) = o;
  }
}

// ---------------- launch ----------------
extern "C" void kernel_launch(void* const* d_in, const int* in_sizes, int n_in,
                              void* d_out, int out_size, void* d_ws, size_t ws_size,
                              hipStream_t stream) {
  (void)in_sizes; (void)n_in; (void)out_size; (void)ws_size;
  const float* x   = (const float*)d_in[0];
  const int* mask  = (const int*)d_in[1];
  const float* wq  = (const float*)d_in[2];
  const float* bq  = (const float*)d_in[3];
  const float* wk  = (const float*)d_in[4];
  const float* bk  = (const float*)d_in[5];
  const float* wv  = (const float*)d_in[6];
  const float* bv  = (const float*)d_in[7];
  const float* wo  = (const float*)d_in[8];
  const float* bo  = (const float*)d_in[9];
  const float* w1  = (const float*)d_in[10];
  const float* b1  = (const float*)d_in[11];
  const float* w2  = (const float*)d_in[12];
  const float* b2  = (const float*)d_in[13];
  const float* g1  = (const float*)d_in[14];
  const float* be1 = (const float*)d_in[15];
  const float* g2  = (const float*)d_in[16];
  const float* be2 = (const float*)d_in[17];

  const int B = 4, S = 2048, D = 1024, H = 16, DFF = 4096;
  const int D3 = 3 * D;
  const size_t TOK = (size_t)B * S;
  const size_t TD = TOK * D;

  u16* ws   = (u16*)d_ws;
  u16* QKVp = ws;                          // [0, 3*TD)
  u16* xb   = ws + 3 * TD;                 // dead after QKV gemm
  u16* VT   = xb;
  u16* CTX  = ws + 4 * TD;
  u16* ATT  = ws + 5 * TD;
  u16* Hb   = ws + 6 * TD;
  u16* QKVT = ws + 7 * TD;                 // 3*D*D
  u16* WOT  = QKVT + 3 * (size_t)D * D;    // D*D
  u16* W1T  = WOT + (size_t)D * D;         // D*DFF
  u16* FF1  = ws;                          // overlays QKVp+VT
  u16* FF2  = ATT;
  u16* W2T  = QKVT;                        // into dead QKVT+WOT
  float* biasc = (float*)CTX;              // dead before flash writes CTX

  dim3 blk(256);

  cvt_bf16<<<dim3((unsigned)(TD / (256 * 4))), blk, 0, stream>>>(x, xb, (int)TD);
  concat3<<<dim3(4), blk, 0, stream>>>(bq, bk, bv, biasc, D);

  transpose_f32_bf16<<<dim3(D / 32, D / 32), blk, 0, stream>>>(wq, QKVT, D, D);
  transpose_f32_bf16<<<dim3(D / 32, D / 32), blk, 0, stream>>>(wk, QKVT + (size_t)D * D, D, D);
  transpose_f32_bf16<<<dim3(D / 32, D / 32), blk, 0, stream>>>(wv, QKVT + 2 * (size_t)D * D, D, D);
  transpose_f32_bf16<<<dim3(D / 32, D / 32), blk, 0, stream>>>(wo, WOT, D, D);
  transpose_f32_bf16<<<dim3(DFF / 32, D / 32), blk, 0, stream>>>(w1, W1T, D, DFF);

  gemm_bt<<<dim3(D3 / 128, TOK / 128), blk, 0, stream>>>(xb, QKVT, biasc, QKVp, (int)TOK, D3, D, 0);

  transpose_v<<<dim3(S / 32, 2, B * H), blk, 0, stream>>>(QKVp, VT, B, S, H, D3, 2 * D);

  flash_attn<<<dim3(S / 64, B * H), dim3(128), 0, stream>>>(
      QKVp, QKVp + D, VT, mask, CTX, B, S, H, D3);

  gemm_bt<<<dim3(D / 128, TOK / 128), blk, 0, stream>>>(CTX, WOT, bo, ATT, (int)TOK, D, D, 0);

  transpose_f32_bf16<<<dim3(D / 32, DFF / 32), blk, 0, stream>>>(w2, W2T, DFF, D);

  add_ln<<<dim3((unsigned)TOK), blk, 0, stream>>>(x, (const u16*)nullptr, ATT, g1, be1,
                                                  Hb, (float*)nullptr, D);

  gemm_bt<<<dim3(DFF / 128, TOK / 128), blk, 0, stream>>>(Hb, W1T, b1, FF1, (int)TOK, DFF, D, 1);
  gemm_bt<<<dim3(D / 128, TOK / 128), blk, 0, stream>>>(FF1, W2T, b2, FF2, (int)TOK, D, DFF, 0);

  add_ln<<<dim3((unsigned)TOK), blk, 0, stream>>>((const float*)nullptr, Hb, FF2, g2, be2,
                                                  (u16*)nullptr, (float*)d_out, D);
}

// Round 6
// 626.588 us; speedup vs baseline: 1.1107x; 1.0259x over previous
//
#include <hip/hip_runtime.h>

typedef unsigned short u16;
typedef __attribute__((ext_vector_type(4))) unsigned short u16x4;
typedef __attribute__((ext_vector_type(8))) short bf16x8;
typedef __attribute__((ext_vector_type(4))) float f32x4;
typedef __attribute__((ext_vector_type(16))) float f32x16;

__device__ inline float bf2f(u16 u) {
  union { unsigned int i; float f; } v; v.i = ((unsigned int)u) << 16; return v.f;
}
__device__ inline u16 f2bf(float f) {
  union { float f; unsigned int i; } v; v.f = f;
  unsigned int r = v.i + 0x7fffu + ((v.i >> 16) & 1u);
  return (u16)(r >> 16);
}
// single-instruction pack of two f32 -> 2xbf16 (T12 primitive; no builtin on gfx950)
__device__ inline unsigned int cvt_pk_bf16(float lo, float hi) {
  unsigned int r;
  asm("v_cvt_pk_bf16_f32 %0, %1, %2" : "=v"(r) : "v"(lo), "v"(hi));
  return r;
}
__device__ inline f32x16 zero16() {
  f32x16 z;
  #pragma unroll
  for (int i = 0; i < 16; ++i) z[i] = 0.f;
  return z;
}

// async global->LDS, 16B per lane; LDS dest must be WAVE-UNIFORM base (m104);
// HW writes lane L at base + L*16. Global src is per-lane.
typedef const __attribute__((address_space(1))) unsigned int* gas_t;
typedef __attribute__((address_space(3))) unsigned int* las_t;
__device__ inline void gload_lds16(const u16* g, u16* l) {
  __builtin_amdgcn_global_load_lds((gas_t)(unsigned long long)(const void*)g,
                                   (las_t)(unsigned int)(unsigned long long)(void*)l,
                                   16, 0, 0);
}

// ---------------- fp32 -> bf16 convert (x) ----------------
__global__ __launch_bounds__(256) void cvt_bf16(const float* __restrict__ src,
                                                u16* __restrict__ dst, int n) {
  int i = (blockIdx.x * 256 + threadIdx.x) * 4;
  if (i >= n) return;
  float4 v = *(const float4*)(src + i);
  u16x4 o;
  o.x = f2bf(v.x); o.y = f2bf(v.y); o.z = f2bf(v.z); o.w = f2bf(v.w);
  *(u16x4*)(dst + i) = o;
}

// ---------------- bias concat (fp32): [bq|bk|bv] -> o[3n] ----------------
__global__ __launch_bounds__(256) void concat3(const float* __restrict__ a,
                                               const float* __restrict__ b,
                                               const float* __restrict__ c,
                                               float* __restrict__ o, int n) {
  int i = blockIdx.x * 256 + threadIdx.x;
  if (i >= n) return;
  o[i] = a[i]; o[n + i] = b[i]; o[2 * n + i] = c[i];
}

// ------------- transpose+convert: fp32 src [R][C] -> bf16 dst [C][R] -------
__global__ __launch_bounds__(256) void transpose_f32_bf16(const float* __restrict__ src,
                                                          u16* __restrict__ dst,
                                                          int R, int C) {
  __shared__ u16 tile[32][33];
  int tx = threadIdx.x & 31, ty = threadIdx.x >> 5;  // 32 x 8
  int c0 = blockIdx.x * 32, r0 = blockIdx.y * 32;
  #pragma unroll
  for (int i = ty; i < 32; i += 8)
    tile[i][tx] = f2bf(src[(size_t)(r0 + i) * C + c0 + tx]);
  __syncthreads();
  #pragma unroll
  for (int i = ty; i < 32; i += 8)
    dst[(size_t)(c0 + i) * R + r0 + tx] = tile[tx][i];
}

// ---- per-head V transpose from packed QKV: src row-stride RS, col offset CO ----
__global__ __launch_bounds__(256) void transpose_v(const u16* __restrict__ src,
                                                   u16* __restrict__ VT,
                                                   int B, int S, int H, int RS, int CO) {
  __shared__ u16 tile[32][33];
  int tx = threadIdx.x & 31, ty = threadIdx.x >> 5;
  int s0 = blockIdx.x * 32, d0 = blockIdx.y * 32;
  int bh = blockIdx.z;
  int b = bh / H, h = bh % H;
  #pragma unroll
  for (int i = ty; i < 32; i += 8)
    tile[i][tx] = src[(size_t)(b * S + s0 + i) * RS + CO + h * 64 + d0 + tx];
  __syncthreads();
  #pragma unroll
  for (int i = ty; i < 32; i += 8)
    VT[((size_t)bh * 64 + d0 + i) * S + s0 + tx] = tile[tx][i];
}

// ---------------- 128^2 GEMM (kept for small-N: WO, FF2) --------------------
__global__ __launch_bounds__(256) void gemm_bt(const u16* __restrict__ A,
                                               const u16* __restrict__ Bt,
                                               const float* __restrict__ bias,
                                               u16* __restrict__ C,
                                               int M, int N, int K, int relu) {
  __shared__ u16 As[128 * 64];
  __shared__ u16 Bs[128 * 64];
  const int tid = threadIdx.x;
  const int lane = tid & 63, wid = tid >> 6;
  const int lr = lane & 15, quad = lane >> 4;
  const int wm = (wid >> 1) * 64, wn = (wid & 1) * 64;
  const int m0 = blockIdx.y * 128, n0 = blockIdx.x * 128;
  const int grow = lane >> 3;                    // row-within-8 (staging)
  const int gcol = ((lane & 7) ^ grow) * 8;      // pre-swizzled source col (u16)
  const int rsw = (lr & 7) << 3;                 // read-side swizzle (u16)

  f32x4 acc[4][4];
  const f32x4 zero = {0.f, 0.f, 0.f, 0.f};
  #pragma unroll
  for (int mt = 0; mt < 4; ++mt)
    #pragma unroll
    for (int nt = 0; nt < 4; ++nt) acc[mt][nt] = zero;

  for (int k0 = 0; k0 < K; k0 += 64) {
    #pragma unroll
    for (int it = 0; it < 4; ++it) {
      int rbase = wid * 32 + it * 8;
      gload_lds16(A + (size_t)(m0 + rbase + grow) * K + k0 + gcol, &As[rbase * 64]);
      gload_lds16(Bt + (size_t)(n0 + rbase + grow) * K + k0 + gcol, &Bs[rbase * 64]);
    }
    __syncthreads();
    #pragma unroll
    for (int kk = 0; kk < 2; ++kk) {
      bf16x8 af[4], bfr[4];
      #pragma unroll
      for (int mt = 0; mt < 4; ++mt)
        af[mt] = *(const bf16x8*)(&As[(wm + mt * 16 + lr) * 64 + ((kk * 32 + quad * 8) ^ rsw)]);
      #pragma unroll
      for (int nt = 0; nt < 4; ++nt)
        bfr[nt] = *(const bf16x8*)(&Bs[(wn + nt * 16 + lr) * 64 + ((kk * 32 + quad * 8) ^ rsw)]);
      #pragma unroll
      for (int mt = 0; mt < 4; ++mt)
        #pragma unroll
        for (int nt = 0; nt < 4; ++nt)
          acc[mt][nt] = __builtin_amdgcn_mfma_f32_16x16x32_bf16(af[mt], bfr[nt], acc[mt][nt], 0, 0, 0);
    }
    __syncthreads();
  }

  #pragma unroll
  for (int nt = 0; nt < 4; ++nt) {
    int n = n0 + wn + nt * 16 + lr;
    float bv = bias[n];
    #pragma unroll
    for (int mt = 0; mt < 4; ++mt) {
      #pragma unroll
      for (int i = 0; i < 4; ++i) {
        int m = m0 + wm + mt * 16 + quad * 4 + i;
        float v = acc[mt][nt][i] + bv;
        if (relu) v = fmaxf(v, 0.f);
        C[(size_t)m * N + n] = f2bf(v);
      }
    }
  }
}

// ---------------- 256^2 8-phase GEMM (T2+T3+T4+T5) for big-N gemms ----------
// 512 thr = 8 waves (2M x 4N), per-wave output 128x64, BK=64, LDS 128KB dbuf.
// Per K-tile: 4 phases, one C-quadrant (mq,nq) each, 16 MFMA/phase.
// Stage schedule (all targets dead >= 1 barrier before the write lands):
//   ph1(0,0): A_mq1(t+1) -> buf ~c   [A(t-1) mq1 region, dead since t-1 ph4]
//   ph2(0,1): Bh0(t+1)   -> buf ~c   [B(t-1) rows 0-127, dead since t-1 ph4]
//   ph3(1,0): Bh1(t+1)   -> buf ~c   [B(t-1) rows 128-255]
//   ph4(1,1): A_mq0(t+2) -> buf c    [A(t) mq0 rows, dead since ph2]
// Counted vmcnt(2) once per tile (never 0 except last tile). One gload = 2
// loads/thread; tile t's 8 loads are always the 8 oldest at its start.
__global__ __launch_bounds__(512, 2) void gemm256(const u16* __restrict__ A,
                                                  const u16* __restrict__ Bt,
                                                  const float* __restrict__ bias,
                                                  u16* __restrict__ C,
                                                  int M, int N, int K, int relu) {
  __shared__ u16 As[2][256][64];
  __shared__ u16 Bs[2][256][64];
  const int tid = threadIdx.x;
  const int lane = tid & 63, wid = tid >> 6;          // 8 waves
  const int lr = lane & 15, quad = lane >> 4;
  const int wm2 = wid >> 2, wn4 = wid & 3;            // 2M x 4N wave grid
  const int m0 = blockIdx.y * 256, n0 = blockIdx.x * 256;
  const int srl = lane >> 3;                          // staging row-within-8
  const int scol = ((lane & 7) ^ srl) * 8;            // pre-swizzled src col (u16)
  const int rsw = (lr & 7) << 3;                      // read-side swizzle (u16)
  const int NT = K >> 6;

  f32x4 acc[8][4];
  #pragma unroll
  for (int mi = 0; mi < 8; ++mi)
    #pragma unroll
    for (int ni = 0; ni < 4; ++ni) {
      acc[mi][ni][0] = 0.f; acc[mi][ni][1] = 0.f;
      acc[mi][ni][2] = 0.f; acc[mi][ni][3] = 0.f;
    }

  // stage helpers: LDS dest wave-uniform; rows wid*8 + srl per lane.
#define STAGE_A(TT, MQ)                                                        \
  if ((TT) < NT) {                                                             \
    int c2 = (TT) & 1, k0s = (TT) << 6;                                        \
    const u16* ga = A + (size_t)(m0 + (MQ) * 64 + wid * 8 + srl) * K + k0s + scol; \
    gload_lds16(ga, &As[c2][(MQ) * 64 + wid * 8][0]);                          \
    gload_lds16(ga + (size_t)128 * K, &As[c2][128 + (MQ) * 64 + wid * 8][0]);  \
  }
#define STAGE_B(TT, HH)                                                        \
  if ((TT) < NT) {                                                             \
    int c2 = (TT) & 1, k0s = (TT) << 6;                                        \
    const u16* gb = Bt + (size_t)(n0 + (HH) * 128 + wid * 8 + srl) * K + k0s + scol; \
    gload_lds16(gb, &Bs[c2][(HH) * 128 + wid * 8][0]);                         \
    gload_lds16(gb + (size_t)64 * K, &Bs[c2][(HH) * 128 + 64 + wid * 8][0]);   \
  }

#define PHASE(MQ, NQ, STAGE_STMT)                                              \
  {                                                                            \
    bf16x8 af[4][2], bfr[2][2];                                                \
    _Pragma("unroll")                                                          \
    for (int mt = 0; mt < 4; ++mt)                                             \
      _Pragma("unroll")                                                        \
      for (int kk = 0; kk < 2; ++kk)                                           \
        af[mt][kk] = *(const bf16x8*)(&As[c][wm2 * 128 + (MQ) * 64 + mt * 16 + lr] \
                                         [(kk * 32 + quad * 8) ^ rsw]);        \
    _Pragma("unroll")                                                          \
    for (int nt = 0; nt < 2; ++nt)                                             \
      _Pragma("unroll")                                                        \
      for (int kk = 0; kk < 2; ++kk)                                           \
        bfr[nt][kk] = *(const bf16x8*)(&Bs[c][wn4 * 64 + (NQ) * 32 + nt * 16 + lr] \
                                          [(kk * 32 + quad * 8) ^ rsw]);       \
    STAGE_STMT;                                                                \
    __builtin_amdgcn_s_barrier();                                              \
    __builtin_amdgcn_s_setprio(1);                                             \
    _Pragma("unroll")                                                          \
    for (int mt = 0; mt < 4; ++mt)                                             \
      _Pragma("unroll")                                                        \
      for (int nt = 0; nt < 2; ++nt)                                           \
        _Pragma("unroll")                                                      \
        for (int kk = 0; kk < 2; ++kk)                                         \
          acc[(MQ) * 4 + mt][(NQ) * 2 + nt] = __builtin_amdgcn_mfma_f32_16x16x32_bf16( \
              af[mt][kk], bfr[nt][kk], acc[(MQ) * 4 + mt][(NQ) * 2 + nt], 0, 0, 0); \
    __builtin_amdgcn_s_setprio(0);                                             \
    __builtin_amdgcn_s_barrier();                                              \
  }

  // prologue: A_mq0(0), A_mq1(0), Bh0(0), Bh1(0), A_mq0(1) = 10 loads/thread
  STAGE_A(0, 0);
  STAGE_A(0, 1);
  STAGE_B(0, 0);
  STAGE_B(0, 1);
  STAGE_A(1, 0);

  for (int t = 0; t < NT; ++t) {
    const int c = t & 1;
    // tile-start: my 8 tile-t loads are the oldest; <=2 newer may stay in flight
    if (t + 1 < NT) {
      asm volatile("s_waitcnt vmcnt(2)" ::: "memory");
    } else {
      asm volatile("s_waitcnt vmcnt(0)" ::: "memory");
    }
    __builtin_amdgcn_s_barrier();
    PHASE(0, 0, STAGE_A(t + 1, 1));
    PHASE(0, 1, STAGE_B(t + 1, 0));
    PHASE(1, 0, STAGE_B(t + 1, 1));
    PHASE(1, 1, STAGE_A(t + 2, 0));
  }
#undef PHASE
#undef STAGE_A
#undef STAGE_B

  #pragma unroll
  for (int ni = 0; ni < 4; ++ni) {
    int n = n0 + wn4 * 64 + ni * 16 + lr;
    float bv = bias[n];
    #pragma unroll
    for (int mi = 0; mi < 8; ++mi) {
      #pragma unroll
      for (int i = 0; i < 4; ++i) {
        int m = m0 + wm2 * 128 + mi * 16 + quad * 4 + i;
        float v = acc[mi][ni][i] + bv;
        if (relu) v = fmaxf(v, 0.f);
        C[(size_t)m * N + n] = f2bf(v);
      }
    }
  }
}

// ---------------- flash attention (S^T, 32 q-rows per wave, 32x32 MFMA) -----
// R3 shape (best measured: 165us): grid (S/128, B*H); block 256 (4 waves).
// In-register P redistribution, ballot mask, raw-domain defer-max.
__global__ __launch_bounds__(256) void flash_attn(const u16* __restrict__ Qp,
                                                  const u16* __restrict__ Kp,
                                                  const u16* __restrict__ VT,
                                                  const int* __restrict__ mask,
                                                  u16* __restrict__ ctx,
                                                  int B, int S, int H, int QSTR) {
  __shared__ u16 kt_lds[64 * 64];        // K tile [k][d], linear; XOR-swizzled data
  __shared__ u16 vt_lds[64 * 64];        // V^T tile [d][k], linear; XOR-swizzled data
  const int tid = threadIdx.x;
  const int lane = tid & 63, wid = tid >> 6;
  const int l31 = lane & 31, hi = lane >> 5;
  const int bh = blockIdx.y;
  const int b = bh / H, h = bh % H;
  const u16* vt_base = VT + (size_t)bh * 64 * S;
  const int* mbase = mask + b * S;
  const float SC = 0.125f * 1.44269504089f;   // 1/sqrt(dk) * log2(e)

  const int srl = lane >> 3;                         // row-within-8
  const int scol = ((lane & 7) ^ srl) * 8;           // pre-swizzled source col (u16)
  const int rsw = (lane & 7) << 3;                   // read-side swizzle

  const int q = blockIdx.x * 128 + wid * 32 + l31;
  bf16x8 qf[4];
  {
    const u16* qptr = Qp + (size_t)(b * S + q) * QSTR + h * 64;
    #pragma unroll
    for (int t = 0; t < 4; ++t)
      qf[t] = *(const bf16x8*)(qptr + t * 16 + hi * 8);
  }

  float m_i = -1e30f, l_i = 0.f;
  f32x16 o0 = zero16(), o1 = zero16();

  const u16* kgp = Kp + ((size_t)b * S + wid * 16 + srl) * QSTR + h * 64 + scol;
  const u16* vgp = vt_base + (size_t)(wid * 16 + srl) * S + scol;
  u16* klb = &kt_lds[(wid * 16) * 64];
  u16* vlb = &vt_lds[(wid * 16) * 64];

  for (int kt = 0; kt < S; kt += 64) {
    gload_lds16(kgp + (size_t)kt * QSTR, klb);
    gload_lds16(kgp + (size_t)(kt + 8) * QSTR, klb + 8 * 64);
    gload_lds16(vgp + kt, vlb);
    gload_lds16(vgp + 8 * (size_t)S + kt, vlb + 8 * 64);
    int mv = mbase[kt + lane];
    unsigned long long bal = __ballot(mv != 0);
    __syncthreads();

    f32x16 sa0 = zero16(), sa1 = zero16();
    const u16* krow0 = &kt_lds[l31 * 64];
    const u16* krow1 = &kt_lds[(32 + l31) * 64];
    __builtin_amdgcn_s_setprio(1);
    #pragma unroll
    for (int dblock = 0; dblock < 4; ++dblock) {
      int c = (dblock * 16 + hi * 8) ^ rsw;
      bf16x8 kf0 = *(const bf16x8*)(krow0 + c);
      bf16x8 kf1 = *(const bf16x8*)(krow1 + c);
      sa0 = __builtin_amdgcn_mfma_f32_32x32x16_bf16(kf0, qf[dblock], sa0, 0, 0, 0);
      sa1 = __builtin_amdgcn_mfma_f32_32x32x16_bf16(kf1, qf[dblock], sa1, 0, 0, 0);
    }
    __builtin_amdgcn_s_setprio(0);

    if (bal != 0xFFFFFFFFFFFFFFFFull) {
      unsigned long long balh = bal >> (hi * 4);
      #pragma unroll
      for (int r = 0; r < 16; ++r) {
        int kloc = (r & 3) + 8 * (r >> 2);
        if (!((balh >> kloc) & 1)) sa0[r] = -2e30f;
        if (!((balh >> (32 + kloc)) & 1)) sa1[r] = -2e30f;
      }
    }

    float tmax = sa0[0];
    #pragma unroll
    for (int r = 1; r < 16; ++r) tmax = fmaxf(tmax, sa0[r]);
    #pragma unroll
    for (int r = 0; r < 16; ++r) tmax = fmaxf(tmax, sa1[r]);
    tmax = fmaxf(tmax, __shfl_xor(tmax, 32, 64));
    if (__any(tmax > m_i + 44.0f)) {
      float mn = fmaxf(m_i, tmax);
      float al = exp2f((m_i - mn) * SC);
      m_i = mn;
      l_i *= al;
      #pragma unroll
      for (int r = 0; r < 16; ++r) { o0[r] *= al; o1[r] *= al; }
    }
    float msc = m_i * SC;
    float rs = 0.f;
    #pragma unroll
    for (int r = 0; r < 16; ++r) {
      float p0 = exp2f(__builtin_fmaf(sa0[r], SC, -msc));
      float p1 = exp2f(__builtin_fmaf(sa1[r], SC, -msc));
      sa0[r] = p0; sa1[r] = p1; rs += p0 + p1;
    }
    l_i += rs;

    unsigned pfw[4][4];
    #pragma unroll
    for (int b1 = 0; b1 < 2; ++b1) {
      #pragma unroll
      for (int pair = 0; pair < 2; ++pair) {
        unsigned X0 = cvt_pk_bf16(sa0[(2 * b1) * 4 + pair * 2], sa0[(2 * b1) * 4 + pair * 2 + 1]);
        unsigned Y0 = cvt_pk_bf16(sa0[(2 * b1 + 1) * 4 + pair * 2], sa0[(2 * b1 + 1) * 4 + pair * 2 + 1]);
        unsigned Xp0 = __shfl_xor(X0, 32, 64);
        unsigned Yp0 = __shfl_xor(Y0, 32, 64);
        pfw[b1][pair] = hi ? Yp0 : X0;
        pfw[b1][pair + 2] = hi ? Y0 : Xp0;
        unsigned X1 = cvt_pk_bf16(sa1[(2 * b1) * 4 + pair * 2], sa1[(2 * b1) * 4 + pair * 2 + 1]);
        unsigned Y1 = cvt_pk_bf16(sa1[(2 * b1 + 1) * 4 + pair * 2], sa1[(2 * b1 + 1) * 4 + pair * 2 + 1]);
        unsigned Xp1 = __shfl_xor(X1, 32, 64);
        unsigned Yp1 = __shfl_xor(Y1, 32, 64);
        pfw[2 + b1][pair] = hi ? Yp1 : X1;
        pfw[2 + b1][pair + 2] = hi ? Y1 : Xp1;
      }
    }

    const u16* vrow0 = &vt_lds[l31 * 64];
    const u16* vrow1 = &vt_lds[(32 + l31) * 64];
    __builtin_amdgcn_s_setprio(1);
    #pragma unroll
    for (int kb = 0; kb < 4; ++kb) {
      int c = (kb * 16 + hi * 8) ^ rsw;
      bf16x8 vf0 = *(const bf16x8*)(vrow0 + c);
      bf16x8 vf1 = *(const bf16x8*)(vrow1 + c);
      union { unsigned w[4]; bf16x8 v; } pu;
      pu.w[0] = pfw[kb][0]; pu.w[1] = pfw[kb][1];
      pu.w[2] = pfw[kb][2]; pu.w[3] = pfw[kb][3];
      o0 = __builtin_amdgcn_mfma_f32_32x32x16_bf16(vf0, pu.v, o0, 0, 0, 0);
      o1 = __builtin_amdgcn_mfma_f32_32x32x16_bf16(vf1, pu.v, o1, 0, 0, 0);
    }
    __builtin_amdgcn_s_setprio(0);
    __syncthreads();
  }

  l_i += __shfl_xor(l_i, 32, 64);
  float linv = 1.f / fmaxf(l_i, 1e-30f);
  u16* op = ctx + (size_t)(b * S + q) * (H * 64) + h * 64;
  #pragma unroll
  for (int rq = 0; rq < 4; ++rq) {
    uint2 w0, w1;
    w0.x = cvt_pk_bf16(o0[rq * 4 + 0] * linv, o0[rq * 4 + 1] * linv);
    w0.y = cvt_pk_bf16(o0[rq * 4 + 2] * linv, o0[rq * 4 + 3] * linv);
    *(uint2*)(op + rq * 8 + hi * 4) = w0;
    w1.x = cvt_pk_bf16(o1[rq * 4 + 0] * linv, o1[rq * 4 + 1] * linv);
    w1.y = cvt_pk_bf16(o1[rq * 4 + 2] * linv, o1[rq * 4 + 3] * linv);
    *(uint2*)(op + 32 + rq * 8 + hi * 4) = w1;
  }
}

// ---------------- fused residual add + LayerNorm (vectorized) ----------------
__device__ inline float block_reduce_sum(float v, float* sbuf) {
  #pragma unroll
  for (int m = 1; m < 64; m <<= 1) v += __shfl_xor(v, m, 64);
  int w = threadIdx.x >> 6;
  if ((threadIdx.x & 63) == 0) sbuf[w] = v;
  __syncthreads();
  v = sbuf[0] + sbuf[1] + sbuf[2] + sbuf[3];
  __syncthreads();
  return v;
}

__global__ __launch_bounds__(256) void add_ln(const float* __restrict__ a32,
                                              const u16* __restrict__ a16,
                                              const u16* __restrict__ b,
                                              const float* __restrict__ g,
                                              const float* __restrict__ be,
                                              u16* __restrict__ out16,
                                              float* __restrict__ out32, int D) {
  __shared__ float sbuf[4];
  int row = blockIdx.x;
  size_t base = (size_t)row * D;
  int i = threadIdx.x * 4;
  float v[4];
  {
    u16x4 bv = *(const u16x4*)(b + base + i);
    if (a32) {
      float4 av = *(const float4*)(a32 + base + i);
      v[0] = av.x + bf2f(bv.x); v[1] = av.y + bf2f(bv.y);
      v[2] = av.z + bf2f(bv.z); v[3] = av.w + bf2f(bv.w);
    } else {
      u16x4 av = *(const u16x4*)(a16 + base + i);
      v[0] = bf2f(av.x) + bf2f(bv.x); v[1] = bf2f(av.y) + bf2f(bv.y);
      v[2] = bf2f(av.z) + bf2f(bv.z); v[3] = bf2f(av.w) + bf2f(bv.w);
    }
  }
  float sum = v[0] + v[1] + v[2] + v[3];
  sum = block_reduce_sum(sum, sbuf);
  float mean = sum / (float)D;
  float var = 0.f;
  #pragma unroll
  for (int j = 0; j < 4; ++j) { float d = v[j] - mean; var += d * d; }
  var = block_reduce_sum(var, sbuf);
  float rstd = rsqrtf(var / (float)D + 1e-5f);
  float4 gv = *(const float4*)(g + i);
  float4 bev = *(const float4*)(be + i);
  float o0 = (v[0] - mean) * rstd * gv.x + bev.x;
  float o1 = (v[1] - mean) * rstd * gv.y + bev.y;
  float o2 = (v[2] - mean) * rstd * gv.z + bev.z;
  float o3 = (v[3] - mean) * rstd * gv.w + bev.w;
  if (out32) {
    float4 o = {o0, o1, o2, o3};
    *(float4*)(out32 + base + i) = o;
  } else {
    u16x4 o;
    o.x = f2bf(o0); o.y = f2bf(o1); o.z = f2bf(o2); o.w = f2bf(o3);
    *(u16x4*)(out16 + base + i) = o;
  }
}

// ---------------- launch ----------------
extern "C" void kernel_launch(void* const* d_in, const int* in_sizes, int n_in,
                              void* d_out, int out_size, void* d_ws, size_t ws_size,
                              hipStream_t stream) {
  (void)in_sizes; (void)n_in; (void)out_size; (void)ws_size;
  const float* x   = (const float*)d_in[0];
  const int* mask  = (const int*)d_in[1];
  const float* wq  = (const float*)d_in[2];
  const float* bq  = (const float*)d_in[3];
  const float* wk  = (const float*)d_in[4];
  const float* bk  = (const float*)d_in[5];
  const float* wv  = (const float*)d_in[6];
  const float* bv  = (const float*)d_in[7];
  const float* wo  = (const float*)d_in[8];
  const float* bo  = (const float*)d_in[9];
  const float* w1  = (const float*)d_in[10];
  const float* b1  = (const float*)d_in[11];
  const float* w2  = (const float*)d_in[12];
  const float* b2  = (const float*)d_in[13];
  const float* g1  = (const float*)d_in[14];
  const float* be1 = (const float*)d_in[15];
  const float* g2  = (const float*)d_in[16];
  const float* be2 = (const float*)d_in[17];

  const int B = 4, S = 2048, D = 1024, H = 16, DFF = 4096;
  const int D3 = 3 * D;
  const size_t TOK = (size_t)B * S;
  const size_t TD = TOK * D;

  u16* ws   = (u16*)d_ws;
  u16* QKVp = ws;                          // [0, 3*TD)
  u16* xb   = ws + 3 * TD;                 // dead after QKV gemm
  u16* VT   = xb;
  u16* CTX  = ws + 4 * TD;
  u16* ATT  = ws + 5 * TD;
  u16* Hb   = ws + 6 * TD;
  u16* QKVT = ws + 7 * TD;                 // 3*D*D
  u16* WOT  = QKVT + 3 * (size_t)D * D;    // D*D
  u16* W1T  = WOT + (size_t)D * D;         // D*DFF
  u16* FF1  = ws;                          // overlays QKVp+VT
  u16* FF2  = ATT;
  u16* W2T  = QKVT;                        // into dead QKVT+WOT
  float* biasc = (float*)CTX;              // dead before flash writes CTX

  dim3 blk(256);

  cvt_bf16<<<dim3((unsigned)(TD / (256 * 4))), blk, 0, stream>>>(x, xb, (int)TD);
  concat3<<<dim3(4), blk, 0, stream>>>(bq, bk, bv, biasc, D);

  transpose_f32_bf16<<<dim3(D / 32, D / 32), blk, 0, stream>>>(wq, QKVT, D, D);
  transpose_f32_bf16<<<dim3(D / 32, D / 32), blk, 0, stream>>>(wk, QKVT + (size_t)D * D, D, D);
  transpose_f32_bf16<<<dim3(D / 32, D / 32), blk, 0, stream>>>(wv, QKVT + 2 * (size_t)D * D, D, D);
  transpose_f32_bf16<<<dim3(D / 32, D / 32), blk, 0, stream>>>(wo, WOT, D, D);
  transpose_f32_bf16<<<dim3(DFF / 32, D / 32), blk, 0, stream>>>(w1, W1T, D, DFF);

  // QKV: 256^2 8-phase (384 blocks)
  gemm256<<<dim3(D3 / 256, TOK / 256), dim3(512), 0, stream>>>(
      xb, QKVT, biasc, QKVp, (int)TOK, D3, D, 0);

  transpose_v<<<dim3(S / 32, 2, B * H), blk, 0, stream>>>(QKVp, VT, B, S, H, D3, 2 * D);

  flash_attn<<<dim3(S / 128, B * H), blk, 0, stream>>>(
      QKVp, QKVp + D, VT, mask, CTX, B, S, H, D3);

  // WO: small N -> 128^2 kernel (512 blocks, full GPU)
  gemm_bt<<<dim3(D / 128, TOK / 128), blk, 0, stream>>>(CTX, WOT, bo, ATT, (int)TOK, D, D, 0);

  transpose_f32_bf16<<<dim3(D / 32, DFF / 32), blk, 0, stream>>>(w2, W2T, DFF, D);

  add_ln<<<dim3((unsigned)TOK), blk, 0, stream>>>(x, (const u16*)nullptr, ATT, g1, be1,
                                                  Hb, (float*)nullptr, D);

  // FF1: 256^2 8-phase (512 blocks = exactly 2 full rounds)
  gemm256<<<dim3(DFF / 256, TOK / 256), dim3(512), 0, stream>>>(
      Hb, W1T, b1, FF1, (int)TOK, DFF, D, 1);
  // FF2: small N -> 128^2 kernel
  gemm_bt<<<dim3(D / 128, TOK / 128), blk, 0, stream>>>(FF1, W2T, b2, FF2, (int)TOK, D, DFF, 0);

  add_ln<<<dim3((unsigned)TOK), blk, 0, stream>>>((const float*)nullptr, Hb, FF2, g2, be2,
                                                  (u16*)nullptr, (float*)d_out, D);
}

// Round 8
// 609.201 us; speedup vs baseline: 1.1424x; 1.0285x over previous
//
#include <hip/hip_runtime.h>

typedef unsigned short u16;
typedef __attribute__((ext_vector_type(4))) unsigned short u16x4;
typedef __attribute__((ext_vector_type(8))) short bf16x8;
typedef __attribute__((ext_vector_type(4))) float f32x4;
typedef __attribute__((ext_vector_type(16))) float f32x16;

__device__ inline float bf2f(u16 u) {
  union { unsigned int i; float f; } v; v.i = ((unsigned int)u) << 16; return v.f;
}
__device__ inline u16 f2bf(float f) {
  union { float f; unsigned int i; } v; v.f = f;
  unsigned int r = v.i + 0x7fffu + ((v.i >> 16) & 1u);
  return (u16)(r >> 16);
}
// single-instruction pack of two f32 -> 2xbf16 (T12 primitive; no builtin on gfx950)
__device__ inline unsigned int cvt_pk_bf16(float lo, float hi) {
  unsigned int r;
  asm("v_cvt_pk_bf16_f32 %0, %1, %2" : "=v"(r) : "v"(lo), "v"(hi));
  return r;
}
__device__ inline f32x16 zero16() {
  f32x16 z;
  #pragma unroll
  for (int i = 0; i < 16; ++i) z[i] = 0.f;
  return z;
}

// async global->LDS, 16B per lane; LDS dest must be WAVE-UNIFORM base (m104);
// HW writes lane L at base + L*16. Global src is per-lane.
typedef const __attribute__((address_space(1))) unsigned int* gas_t;
typedef __attribute__((address_space(3))) unsigned int* las_t;
__device__ inline void gload_lds16(const u16* g, u16* l) {
  __builtin_amdgcn_global_load_lds((gas_t)(unsigned long long)(const void*)g,
                                   (las_t)(unsigned int)(unsigned long long)(void*)l,
                                   16, 0, 0);
}

// ---------------- fp32 -> bf16 convert (x) ----------------
__global__ __launch_bounds__(256) void cvt_bf16(const float* __restrict__ src,
                                                u16* __restrict__ dst, int n) {
  int i = (blockIdx.x * 256 + threadIdx.x) * 4;
  if (i >= n) return;
  float4 v = *(const float4*)(src + i);
  u16x4 o;
  o.x = f2bf(v.x); o.y = f2bf(v.y); o.z = f2bf(v.z); o.w = f2bf(v.w);
  *(u16x4*)(dst + i) = o;
}

// ---------------- bias concat (fp32): [bq|bk|bv] -> o[3n] ----------------
__global__ __launch_bounds__(256) void concat3(const float* __restrict__ a,
                                               const float* __restrict__ b,
                                               const float* __restrict__ c,
                                               float* __restrict__ o, int n) {
  int i = blockIdx.x * 256 + threadIdx.x;
  if (i >= n) return;
  o[i] = a[i]; o[n + i] = b[i]; o[2 * n + i] = c[i];
}

// ------------- transpose+convert: fp32 src [R][C] -> bf16 dst [C][R] -------
__global__ __launch_bounds__(256) void transpose_f32_bf16(const float* __restrict__ src,
                                                          u16* __restrict__ dst,
                                                          int R, int C) {
  __shared__ u16 tile[32][33];
  int tx = threadIdx.x & 31, ty = threadIdx.x >> 5;  // 32 x 8
  int c0 = blockIdx.x * 32, r0 = blockIdx.y * 32;
  #pragma unroll
  for (int i = ty; i < 32; i += 8)
    tile[i][tx] = f2bf(src[(size_t)(r0 + i) * C + c0 + tx]);
  __syncthreads();
  #pragma unroll
  for (int i = ty; i < 32; i += 8)
    dst[(size_t)(c0 + i) * R + r0 + tx] = tile[tx][i];
}

// ---- per-head V transpose from packed QKV: src row-stride RS, col offset CO ----
__global__ __launch_bounds__(256) void transpose_v(const u16* __restrict__ src,
                                                   u16* __restrict__ VT,
                                                   int B, int S, int H, int RS, int CO) {
  __shared__ u16 tile[32][33];
  int tx = threadIdx.x & 31, ty = threadIdx.x >> 5;
  int s0 = blockIdx.x * 32, d0 = blockIdx.y * 32;
  int bh = blockIdx.z;
  int b = bh / H, h = bh % H;
  #pragma unroll
  for (int i = ty; i < 32; i += 8)
    tile[i][tx] = src[(size_t)(b * S + s0 + i) * RS + CO + h * 64 + d0 + tx];
  __syncthreads();
  #pragma unroll
  for (int i = ty; i < 32; i += 8)
    VT[((size_t)bh * 64 + d0 + i) * S + s0 + tx] = tile[tx][i];
}

// ---------------- 128^2 GEMM (kept for small-N: WO, FF2) --------------------
__global__ __launch_bounds__(256) void gemm_bt(const u16* __restrict__ A,
                                               const u16* __restrict__ Bt,
                                               const float* __restrict__ bias,
                                               u16* __restrict__ C,
                                               int M, int N, int K, int relu) {
  __shared__ u16 As[128 * 64];
  __shared__ u16 Bs[128 * 64];
  const int tid = threadIdx.x;
  const int lane = tid & 63, wid = tid >> 6;
  const int lr = lane & 15, quad = lane >> 4;
  const int wm = (wid >> 1) * 64, wn = (wid & 1) * 64;
  const int m0 = blockIdx.y * 128, n0 = blockIdx.x * 128;
  const int grow = lane >> 3;                    // row-within-8 (staging)
  const int gcol = ((lane & 7) ^ grow) * 8;      // pre-swizzled source col (u16)
  const int rsw = (lr & 7) << 3;                 // read-side swizzle (u16)

  f32x4 acc[4][4];
  const f32x4 zero = {0.f, 0.f, 0.f, 0.f};
  #pragma unroll
  for (int mt = 0; mt < 4; ++mt)
    #pragma unroll
    for (int nt = 0; nt < 4; ++nt) acc[mt][nt] = zero;

  for (int k0 = 0; k0 < K; k0 += 64) {
    #pragma unroll
    for (int it = 0; it < 4; ++it) {
      int rbase = wid * 32 + it * 8;
      gload_lds16(A + (size_t)(m0 + rbase + grow) * K + k0 + gcol, &As[rbase * 64]);
      gload_lds16(Bt + (size_t)(n0 + rbase + grow) * K + k0 + gcol, &Bs[rbase * 64]);
    }
    __syncthreads();
    #pragma unroll
    for (int kk = 0; kk < 2; ++kk) {
      bf16x8 af[4], bfr[4];
      #pragma unroll
      for (int mt = 0; mt < 4; ++mt)
        af[mt] = *(const bf16x8*)(&As[(wm + mt * 16 + lr) * 64 + ((kk * 32 + quad * 8) ^ rsw)]);
      #pragma unroll
      for (int nt = 0; nt < 4; ++nt)
        bfr[nt] = *(const bf16x8*)(&Bs[(wn + nt * 16 + lr) * 64 + ((kk * 32 + quad * 8) ^ rsw)]);
      #pragma unroll
      for (int mt = 0; mt < 4; ++mt)
        #pragma unroll
        for (int nt = 0; nt < 4; ++nt)
          acc[mt][nt] = __builtin_amdgcn_mfma_f32_16x16x32_bf16(af[mt], bfr[nt], acc[mt][nt], 0, 0, 0);
    }
    __syncthreads();
  }

  #pragma unroll
  for (int nt = 0; nt < 4; ++nt) {
    int n = n0 + wn + nt * 16 + lr;
    float bv = bias[n];
    #pragma unroll
    for (int mt = 0; mt < 4; ++mt) {
      #pragma unroll
      for (int i = 0; i < 4; ++i) {
        int m = m0 + wm + mt * 16 + quad * 4 + i;
        float v = acc[mt][nt][i] + bv;
        if (relu) v = fmaxf(v, 0.f);
        C[(size_t)m * N + n] = f2bf(v);
      }
    }
  }
}

// ---------------- 256^2 8-phase GEMM (T2+T3+T4+T5), R8 deep-cover schedule --
// 512 thr = 8 waves (2M x 4N), BK=64, 2 K-steps/iter (even->buf0, odd->buf1).
// Half-tiles: A0 = A rows {0-63,128-191}, A1 = {64-127,192-255}, B0 = B rows
// 0-127, B1 = 128-255. Per iter (t even): 8 phases = quadrants
// (t:00,01,10,11),(t+1:00,01,10,11). A-fragments hoisted per mq-pair.
// Stage slots / waits (stages land in regions dead >=2 barriers; waits target
// loads issued >=2-4 phases earlier):
//   p1: B0(t+1)           p5: B0(t+2)
//   p2: B1(t+1)  W4       p6: B1(t+2)  W6
//   p3: A1(t+1)           p7: A0(t+3)
//   p4: A0(t+2)  W4       p8: A1(t+2)  W4
// Final iteration peeled: later stages dropped; waits W4, W2, W0, none.
// Stage helpers are LAMBDAS (not macros): brace-blocks with top-level commas
// cannot pass through nested macro args (R7 compile failure).
__global__ __launch_bounds__(512, 2) void gemm256(const u16* __restrict__ A,
                                                  const u16* __restrict__ Bt,
                                                  const float* __restrict__ bias,
                                                  u16* __restrict__ C,
                                                  int M, int N, int K, int relu) {
  __shared__ u16 As[2][256][64];
  __shared__ u16 Bs[2][256][64];
  const int tid = threadIdx.x;
  const int lane = tid & 63, wid = tid >> 6;          // 8 waves
  const int lr = lane & 15, quad = lane >> 4;
  const int wm2 = wid >> 2, wn4 = wid & 3;            // 2M x 4N wave grid
  const int m0 = blockIdx.y * 256, n0 = blockIdx.x * 256;
  const int srl = lane >> 3;                          // staging row-within-8
  const int scol = ((lane & 7) ^ srl) * 8;            // pre-swizzled src col (u16)
  const int rsw = (lr & 7) << 3;                      // read-side swizzle (u16)
  const int NT = K >> 6;

  f32x4 acc[8][4];
  #pragma unroll
  for (int mi = 0; mi < 8; ++mi)
    #pragma unroll
    for (int ni = 0; ni < 4; ++ni) {
      acc[mi][ni][0] = 0.f; acc[mi][ni][1] = 0.f;
      acc[mi][ni][2] = 0.f; acc[mi][ni][3] = 0.f;
    }

  auto stageA = [&](int TT, int MQ) {
    int c2 = TT & 1;
    int k0s = TT << 6;
    const u16* ga = A + (size_t)(m0 + MQ * 64 + wid * 8 + srl) * K + k0s + scol;
    gload_lds16(ga, &As[c2][MQ * 64 + wid * 8][0]);
    gload_lds16(ga + (size_t)128 * K, &As[c2][128 + MQ * 64 + wid * 8][0]);
  };
  auto stageB = [&](int TT, int HH) {
    int c2 = TT & 1;
    int k0s = TT << 6;
    const u16* gb = Bt + (size_t)(n0 + HH * 128 + wid * 8 + srl) * K + k0s + scol;
    gload_lds16(gb, &Bs[c2][HH * 128 + wid * 8][0]);
    gload_lds16(gb + (size_t)64 * K, &Bs[c2][HH * 128 + 64 + wid * 8][0]);
  };

#define W4 asm volatile("s_waitcnt vmcnt(4)" ::: "memory")
#define W6 asm volatile("s_waitcnt vmcnt(6)" ::: "memory")
#define W2 asm volatile("s_waitcnt vmcnt(2)" ::: "memory")
#define W0 asm volatile("s_waitcnt vmcnt(0)" ::: "memory")
#define WN ((void)0)

  // sub-phase: bfr read (nq) + stage + barrier + MFMA + wait + barrier
#define SUBPHASE(CC, MQ, NQ, STAGE_STMT, WAIT_STMT)                            \
  {                                                                            \
    bf16x8 bfr[2][2];                                                          \
    _Pragma("unroll")                                                          \
    for (int nt = 0; nt < 2; ++nt)                                             \
      _Pragma("unroll")                                                        \
      for (int kk = 0; kk < 2; ++kk)                                           \
        bfr[nt][kk] = *(const bf16x8*)(&Bs[CC][wn4 * 64 + (NQ) * 32 + nt * 16 + lr] \
                                          [(kk * 32 + quad * 8) ^ rsw]);       \
    STAGE_STMT;                                                                \
    __builtin_amdgcn_s_barrier();                                              \
    __builtin_amdgcn_s_setprio(1);                                             \
    _Pragma("unroll")                                                          \
    for (int mt = 0; mt < 4; ++mt)                                             \
      _Pragma("unroll")                                                        \
      for (int nt = 0; nt < 2; ++nt)                                           \
        _Pragma("unroll")                                                      \
        for (int kk = 0; kk < 2; ++kk)                                         \
          acc[(MQ) * 4 + mt][(NQ) * 2 + nt] = __builtin_amdgcn_mfma_f32_16x16x32_bf16( \
              af[mt][kk], bfr[nt][kk], acc[(MQ) * 4 + mt][(NQ) * 2 + nt], 0, 0, 0); \
    __builtin_amdgcn_s_setprio(0);                                             \
    WAIT_STMT;                                                                 \
    __builtin_amdgcn_s_barrier();                                              \
  }

  // pair: hoist af (mq) across the two nq sub-phases
#define PAIR(CC, MQ, ST1, WT1, ST2, WT2)                                       \
  {                                                                            \
    bf16x8 af[4][2];                                                           \
    _Pragma("unroll")                                                          \
    for (int mt = 0; mt < 4; ++mt)                                             \
      _Pragma("unroll")                                                        \
      for (int kk = 0; kk < 2; ++kk)                                           \
        af[mt][kk] = *(const bf16x8*)(&As[CC][wm2 * 128 + (MQ) * 64 + mt * 16 + lr] \
                                         [(kk * 32 + quad * 8) ^ rsw]);        \
    SUBPHASE(CC, MQ, 0, ST1, WT1)                                              \
    SUBPHASE(CC, MQ, 1, ST2, WT2)                                              \
  }

  // prologue: A0(0),B0(0),B1(0),A0(1),A1(0); W4 completes the first three
  stageA(0, 0);
  stageB(0, 0);
  stageB(0, 1);
  stageA(1, 0);
  stageA(0, 1);
  W4;
  __builtin_amdgcn_s_barrier();

  for (int t = 0; t + 2 < NT; t += 2) {
    PAIR(0, 0, stageB(t + 1, 0), WN, stageB(t + 1, 1), W4)
    PAIR(0, 1, stageA(t + 1, 1), WN, stageA(t + 2, 0), W4)
    PAIR(1, 0, stageB(t + 2, 0), WN, stageB(t + 2, 1), W6)
    PAIR(1, 1, stageA(t + 3, 0), WN, stageA(t + 2, 1), W4)
  }
  {
    const int t = NT - 2;               // final iteration, conservative waits
    PAIR(0, 0, stageB(t + 1, 0), WN, stageB(t + 1, 1), W4)
    PAIR(0, 1, stageA(t + 1, 1), WN, WN, W2)
    PAIR(1, 0, WN, WN, WN, W0)
    PAIR(1, 1, WN, WN, WN, WN)
  }
#undef PAIR
#undef SUBPHASE
#undef W4
#undef W6
#undef W2
#undef W0
#undef WN

  #pragma unroll
  for (int ni = 0; ni < 4; ++ni) {
    int n = n0 + wn4 * 64 + ni * 16 + lr;
    float bv = bias[n];
    #pragma unroll
    for (int mi = 0; mi < 8; ++mi) {
      #pragma unroll
      for (int i = 0; i < 4; ++i) {
        int m = m0 + wm2 * 128 + mi * 16 + quad * 4 + i;
        float v = acc[mi][ni][i] + bv;
        if (relu) v = fmaxf(v, 0.f);
        C[(size_t)m * N + n] = f2bf(v);
      }
    }
  }
}

// ---------------- flash attention (S^T, 32 q-rows per wave, 32x32 MFMA) -----
// R3 shape (best measured: 165us): grid (S/128, B*H); block 256 (4 waves).
// In-register P redistribution, ballot mask, raw-domain defer-max.
__global__ __launch_bounds__(256) void flash_attn(const u16* __restrict__ Qp,
                                                  const u16* __restrict__ Kp,
                                                  const u16* __restrict__ VT,
                                                  const int* __restrict__ mask,
                                                  u16* __restrict__ ctx,
                                                  int B, int S, int H, int QSTR) {
  __shared__ u16 kt_lds[64 * 64];        // K tile [k][d], linear; XOR-swizzled data
  __shared__ u16 vt_lds[64 * 64];        // V^T tile [d][k], linear; XOR-swizzled data
  const int tid = threadIdx.x;
  const int lane = tid & 63, wid = tid >> 6;
  const int l31 = lane & 31, hi = lane >> 5;
  const int bh = blockIdx.y;
  const int b = bh / H, h = bh % H;
  const u16* vt_base = VT + (size_t)bh * 64 * S;
  const int* mbase = mask + b * S;
  const float SC = 0.125f * 1.44269504089f;   // 1/sqrt(dk) * log2(e)

  const int srl = lane >> 3;                         // row-within-8
  const int scol = ((lane & 7) ^ srl) * 8;           // pre-swizzled source col (u16)
  const int rsw = (lane & 7) << 3;                   // read-side swizzle

  const int q = blockIdx.x * 128 + wid * 32 + l31;
  bf16x8 qf[4];
  {
    const u16* qptr = Qp + (size_t)(b * S + q) * QSTR + h * 64;
    #pragma unroll
    for (int t = 0; t < 4; ++t)
      qf[t] = *(const bf16x8*)(qptr + t * 16 + hi * 8);
  }

  float m_i = -1e30f, l_i = 0.f;
  f32x16 o0 = zero16(), o1 = zero16();

  const u16* kgp = Kp + ((size_t)b * S + wid * 16 + srl) * QSTR + h * 64 + scol;
  const u16* vgp = vt_base + (size_t)(wid * 16 + srl) * S + scol;
  u16* klb = &kt_lds[(wid * 16) * 64];
  u16* vlb = &vt_lds[(wid * 16) * 64];

  for (int kt = 0; kt < S; kt += 64) {
    gload_lds16(kgp + (size_t)kt * QSTR, klb);
    gload_lds16(kgp + (size_t)(kt + 8) * QSTR, klb + 8 * 64);
    gload_lds16(vgp + kt, vlb);
    gload_lds16(vgp + 8 * (size_t)S + kt, vlb + 8 * 64);
    int mv = mbase[kt + lane];
    unsigned long long bal = __ballot(mv != 0);
    __syncthreads();

    f32x16 sa0 = zero16(), sa1 = zero16();
    const u16* krow0 = &kt_lds[l31 * 64];
    const u16* krow1 = &kt_lds[(32 + l31) * 64];
    __builtin_amdgcn_s_setprio(1);
    #pragma unroll
    for (int dblock = 0; dblock < 4; ++dblock) {
      int c = (dblock * 16 + hi * 8) ^ rsw;
      bf16x8 kf0 = *(const bf16x8*)(krow0 + c);
      bf16x8 kf1 = *(const bf16x8*)(krow1 + c);
      sa0 = __builtin_amdgcn_mfma_f32_32x32x16_bf16(kf0, qf[dblock], sa0, 0, 0, 0);
      sa1 = __builtin_amdgcn_mfma_f32_32x32x16_bf16(kf1, qf[dblock], sa1, 0, 0, 0);
    }
    __builtin_amdgcn_s_setprio(0);

    if (bal != 0xFFFFFFFFFFFFFFFFull) {
      unsigned long long balh = bal >> (hi * 4);
      #pragma unroll
      for (int r = 0; r < 16; ++r) {
        int kloc = (r & 3) + 8 * (r >> 2);
        if (!((balh >> kloc) & 1)) sa0[r] = -2e30f;
        if (!((balh >> (32 + kloc)) & 1)) sa1[r] = -2e30f;
      }
    }

    float tmax = sa0[0];
    #pragma unroll
    for (int r = 1; r < 16; ++r) tmax = fmaxf(tmax, sa0[r]);
    #pragma unroll
    for (int r = 0; r < 16; ++r) tmax = fmaxf(tmax, sa1[r]);
    tmax = fmaxf(tmax, __shfl_xor(tmax, 32, 64));
    if (__any(tmax > m_i + 44.0f)) {
      float mn = fmaxf(m_i, tmax);
      float al = exp2f((m_i - mn) * SC);
      m_i = mn;
      l_i *= al;
      #pragma unroll
      for (int r = 0; r < 16; ++r) { o0[r] *= al; o1[r] *= al; }
    }
    float msc = m_i * SC;
    float rs = 0.f;
    #pragma unroll
    for (int r = 0; r < 16; ++r) {
      float p0 = exp2f(__builtin_fmaf(sa0[r], SC, -msc));
      float p1 = exp2f(__builtin_fmaf(sa1[r], SC, -msc));
      sa0[r] = p0; sa1[r] = p1; rs += p0 + p1;
    }
    l_i += rs;

    unsigned pfw[4][4];
    #pragma unroll
    for (int b1 = 0; b1 < 2; ++b1) {
      #pragma unroll
      for (int pair = 0; pair < 2; ++pair) {
        unsigned X0 = cvt_pk_bf16(sa0[(2 * b1) * 4 + pair * 2], sa0[(2 * b1) * 4 + pair * 2 + 1]);
        unsigned Y0 = cvt_pk_bf16(sa0[(2 * b1 + 1) * 4 + pair * 2], sa0[(2 * b1 + 1) * 4 + pair * 2 + 1]);
        unsigned Xp0 = __shfl_xor(X0, 32, 64);
        unsigned Yp0 = __shfl_xor(Y0, 32, 64);
        pfw[b1][pair] = hi ? Yp0 : X0;
        pfw[b1][pair + 2] = hi ? Y0 : Xp0;
        unsigned X1 = cvt_pk_bf16(sa1[(2 * b1) * 4 + pair * 2], sa1[(2 * b1) * 4 + pair * 2 + 1]);
        unsigned Y1 = cvt_pk_bf16(sa1[(2 * b1 + 1) * 4 + pair * 2], sa1[(2 * b1 + 1) * 4 + pair * 2 + 1]);
        unsigned Xp1 = __shfl_xor(X1, 32, 64);
        unsigned Yp1 = __shfl_xor(Y1, 32, 64);
        pfw[2 + b1][pair] = hi ? Yp1 : X1;
        pfw[2 + b1][pair + 2] = hi ? Y1 : Xp1;
      }
    }

    const u16* vrow0 = &vt_lds[l31 * 64];
    const u16* vrow1 = &vt_lds[(32 + l31) * 64];
    __builtin_amdgcn_s_setprio(1);
    #pragma unroll
    for (int kb = 0; kb < 4; ++kb) {
      int c = (kb * 16 + hi * 8) ^ rsw;
      bf16x8 vf0 = *(const bf16x8*)(vrow0 + c);
      bf16x8 vf1 = *(const bf16x8*)(vrow1 + c);
      union { unsigned w[4]; bf16x8 v; } pu;
      pu.w[0] = pfw[kb][0]; pu.w[1] = pfw[kb][1];
      pu.w[2] = pfw[kb][2]; pu.w[3] = pfw[kb][3];
      o0 = __builtin_amdgcn_mfma_f32_32x32x16_bf16(vf0, pu.v, o0, 0, 0, 0);
      o1 = __builtin_amdgcn_mfma_f32_32x32x16_bf16(vf1, pu.v, o1, 0, 0, 0);
    }
    __builtin_amdgcn_s_setprio(0);
    __syncthreads();
  }

  l_i += __shfl_xor(l_i, 32, 64);
  float linv = 1.f / fmaxf(l_i, 1e-30f);
  u16* op = ctx + (size_t)(b * S + q) * (H * 64) + h * 64;
  #pragma unroll
  for (int rq = 0; rq < 4; ++rq) {
    uint2 w0, w1;
    w0.x = cvt_pk_bf16(o0[rq * 4 + 0] * linv, o0[rq * 4 + 1] * linv);
    w0.y = cvt_pk_bf16(o0[rq * 4 + 2] * linv, o0[rq * 4 + 3] * linv);
    *(uint2*)(op + rq * 8 + hi * 4) = w0;
    w1.x = cvt_pk_bf16(o1[rq * 4 + 0] * linv, o1[rq * 4 + 1] * linv);
    w1.y = cvt_pk_bf16(o1[rq * 4 + 2] * linv, o1[rq * 4 + 3] * linv);
    *(uint2*)(op + 32 + rq * 8 + hi * 4) = w1;
  }
}

// ---------------- fused residual add + LayerNorm (vectorized) ----------------
__device__ inline float block_reduce_sum(float v, float* sbuf) {
  #pragma unroll
  for (int m = 1; m < 64; m <<= 1) v += __shfl_xor(v, m, 64);
  int w = threadIdx.x >> 6;
  if ((threadIdx.x & 63) == 0) sbuf[w] = v;
  __syncthreads();
  v = sbuf[0] + sbuf[1] + sbuf[2] + sbuf[3];
  __syncthreads();
  return v;
}

__global__ __launch_bounds__(256) void add_ln(const float* __restrict__ a32,
                                              const u16* __restrict__ a16,
                                              const u16* __restrict__ b,
                                              const float* __restrict__ g,
                                              const float* __restrict__ be,
                                              u16* __restrict__ out16,
                                              float* __restrict__ out32, int D) {
  __shared__ float sbuf[4];
  int row = blockIdx.x;
  size_t base = (size_t)row * D;
  int i = threadIdx.x * 4;
  float v[4];
  {
    u16x4 bv = *(const u16x4*)(b + base + i);
    if (a32) {
      float4 av = *(const float4*)(a32 + base + i);
      v[0] = av.x + bf2f(bv.x); v[1] = av.y + bf2f(bv.y);
      v[2] = av.z + bf2f(bv.z); v[3] = av.w + bf2f(bv.w);
    } else {
      u16x4 av = *(const u16x4*)(a16 + base + i);
      v[0] = bf2f(av.x) + bf2f(bv.x); v[1] = bf2f(av.y) + bf2f(bv.y);
      v[2] = bf2f(av.z) + bf2f(bv.z); v[3] = bf2f(av.w) + bf2f(bv.w);
    }
  }
  float sum = v[0] + v[1] + v[2] + v[3];
  sum = block_reduce_sum(sum, sbuf);
  float mean = sum / (float)D;
  float var = 0.f;
  #pragma unroll
  for (int j = 0; j < 4; ++j) { float d = v[j] - mean; var += d * d; }
  var = block_reduce_sum(var, sbuf);
  float rstd = rsqrtf(var / (float)D + 1e-5f);
  float4 gv = *(const float4*)(g + i);
  float4 bev = *(const float4*)(be + i);
  float o0 = (v[0] - mean) * rstd * gv.x + bev.x;
  float o1 = (v[1] - mean) * rstd * gv.y + bev.y;
  float o2 = (v[2] - mean) * rstd * gv.z + bev.z;
  float o3 = (v[3] - mean) * rstd * gv.w + bev.w;
  if (out32) {
    float4 o = {o0, o1, o2, o3};
    *(float4*)(out32 + base + i) = o;
  } else {
    u16x4 o;
    o.x = f2bf(o0); o.y = f2bf(o1); o.z = f2bf(o2); o.w = f2bf(o3);
    *(u16x4*)(out16 + base + i) = o;
  }
}

// ---------------- launch ----------------
extern "C" void kernel_launch(void* const* d_in, const int* in_sizes, int n_in,
                              void* d_out, int out_size, void* d_ws, size_t ws_size,
                              hipStream_t stream) {
  (void)in_sizes; (void)n_in; (void)out_size; (void)ws_size;
  const float* x   = (const float*)d_in[0];
  const int* mask  = (const int*)d_in[1];
  const float* wq  = (const float*)d_in[2];
  const float* bq  = (const float*)d_in[3];
  const float* wk  = (const float*)d_in[4];
  const float* bk  = (const float*)d_in[5];
  const float* wv  = (const float*)d_in[6];
  const float* bv  = (const float*)d_in[7];
  const float* wo  = (const float*)d_in[8];
  const float* bo  = (const float*)d_in[9];
  const float* w1  = (const float*)d_in[10];
  const float* b1  = (const float*)d_in[11];
  const float* w2  = (const float*)d_in[12];
  const float* b2  = (const float*)d_in[13];
  const float* g1  = (const float*)d_in[14];
  const float* be1 = (const float*)d_in[15];
  const float* g2  = (const float*)d_in[16];
  const float* be2 = (const float*)d_in[17];

  const int B = 4, S = 2048, D = 1024, H = 16, DFF = 4096;
  const int D3 = 3 * D;
  const size_t TOK = (size_t)B * S;
  const size_t TD = TOK * D;

  u16* ws   = (u16*)d_ws;
  u16* QKVp = ws;                          // [0, 3*TD)
  u16* xb   = ws + 3 * TD;                 // dead after QKV gemm
  u16* VT   = xb;
  u16* CTX  = ws + 4 * TD;
  u16* ATT  = ws + 5 * TD;
  u16* Hb   = ws + 6 * TD;
  u16* QKVT = ws + 7 * TD;                 // 3*D*D
  u16* WOT  = QKVT + 3 * (size_t)D * D;    // D*D
  u16* W1T  = WOT + (size_t)D * D;         // D*DFF
  u16* FF1  = ws;                          // overlays QKVp+VT
  u16* FF2  = ATT;
  u16* W2T  = QKVT;                        // into dead QKVT+WOT
  float* biasc = (float*)CTX;              // dead before flash writes CTX

  dim3 blk(256);

  cvt_bf16<<<dim3((unsigned)(TD / (256 * 4))), blk, 0, stream>>>(x, xb, (int)TD);
  concat3<<<dim3(4), blk, 0, stream>>>(bq, bk, bv, biasc, D);

  transpose_f32_bf16<<<dim3(D / 32, D / 32), blk, 0, stream>>>(wq, QKVT, D, D);
  transpose_f32_bf16<<<dim3(D / 32, D / 32), blk, 0, stream>>>(wk, QKVT + (size_t)D * D, D, D);
  transpose_f32_bf16<<<dim3(D / 32, D / 32), blk, 0, stream>>>(wv, QKVT + 2 * (size_t)D * D, D, D);
  transpose_f32_bf16<<<dim3(D / 32, D / 32), blk, 0, stream>>>(wo, WOT, D, D);
  transpose_f32_bf16<<<dim3(DFF / 32, D / 32), blk, 0, stream>>>(w1, W1T, D, DFF);

  // QKV: 256^2 8-phase (384 blocks)
  gemm256<<<dim3(D3 / 256, TOK / 256), dim3(512), 0, stream>>>(
      xb, QKVT, biasc, QKVp, (int)TOK, D3, D, 0);

  transpose_v<<<dim3(S / 32, 2, B * H), blk, 0, stream>>>(QKVp, VT, B, S, H, D3, 2 * D);

  flash_attn<<<dim3(S / 128, B * H), blk, 0, stream>>>(
      QKVp, QKVp + D, VT, mask, CTX, B, S, H, D3);

  // WO: small N -> 128^2 kernel (512 blocks, full GPU)
  gemm_bt<<<dim3(D / 128, TOK / 128), blk, 0, stream>>>(CTX, WOT, bo, ATT, (int)TOK, D, D, 0);

  transpose_f32_bf16<<<dim3(D / 32, DFF / 32), blk, 0, stream>>>(w2, W2T, DFF, D);

  add_ln<<<dim3((unsigned)TOK), blk, 0, stream>>>(x, (const u16*)nullptr, ATT, g1, be1,
                                                  Hb, (float*)nullptr, D);

  // FF1: 256^2 8-phase (512 blocks = exactly 2 full rounds)
  gemm256<<<dim3(DFF / 256, TOK / 256), dim3(512), 0, stream>>>(
      Hb, W1T, b1, FF1, (int)TOK, DFF, D, 1);
  // FF2: small N -> 128^2 kernel
  gemm_bt<<<dim3(D / 128, TOK / 128), blk, 0, stream>>>(FF1, W2T, b2, FF2, (int)TOK, D, DFF, 0);

  add_ln<<<dim3((unsigned)TOK), blk, 0, stream>>>((const float*)nullptr, Hb, FF2, g2, be2,
                                                  (u16*)nullptr, (float*)d_out, D);
}